// Round 3
// baseline (1547.547 us; speedup 1.0000x reference)
//
#include <hip/hip_runtime.h>

#define NN 256
#define CC 512
#define OO 1024
#define BB 64

#define F_QR 0.1f
#define F_KR 0.1f
#define F_SVE 0.1f

__device__ inline float4 bn4(float4 v, float sc, float hh) {
  return make_float4(v.x * sc + hh, v.y * sc + hh, v.z * sc + hh, v.w * sc + hh);
}

// ---------------- K0: pad rel rows 511 -> 512 (enables aligned float4 rel loads)
__global__ void k_relpad(const float* __restrict__ rel, float* __restrict__ relp) {
  const int row = blockIdx.x;
  const int t = threadIdx.x;
  for (int u = t; u < 511; u += 256) relp[row * 512 + u] = rel[row * 511 + u];
  if (t == 0) relp[row * 512 + 511] = 0.f;
}

// ---------------- K1: qkv[b][o][n] = sum_c W[o][c] * x[b][n][c] ----------------
__global__ __launch_bounds__(256) void k_qkv_gemm(const float* __restrict__ x,
                                                  const float* __restrict__ w,
                                                  float* __restrict__ qkv) {
  const int b = blockIdx.z, ot = blockIdx.y, nt = blockIdx.x;
  const int o0 = ot * 128, n0 = nt * 128;
  __shared__ float As[32][132];
  __shared__ float Bs[32][132];
  const int t = threadIdx.x;
  const int to = t >> 4, tn = t & 15;
  float acc[8][8];
#pragma unroll
  for (int i = 0; i < 8; ++i)
#pragma unroll
    for (int j = 0; j < 8; ++j) acc[i][j] = 0.f;

  const float* wbase = w + (size_t)o0 * CC;
  const float* xbase = x + (size_t)b * NN * CC + (size_t)n0 * CC;

  for (int c0 = 0; c0 < CC; c0 += 32) {
#pragma unroll
    for (int r = 0; r < 4; ++r) {
      int f = t + 256 * r;
      int row = f >> 3, cq = f & 7;
      float4 w4 = *(const float4*)(wbase + (size_t)row * CC + c0 + cq * 4);
      As[cq * 4 + 0][row] = w4.x; As[cq * 4 + 1][row] = w4.y;
      As[cq * 4 + 2][row] = w4.z; As[cq * 4 + 3][row] = w4.w;
      float4 x4 = *(const float4*)(xbase + (size_t)row * CC + c0 + cq * 4);
      Bs[cq * 4 + 0][row] = x4.x; Bs[cq * 4 + 1][row] = x4.y;
      Bs[cq * 4 + 2][row] = x4.z; Bs[cq * 4 + 3][row] = x4.w;
    }
    __syncthreads();
#pragma unroll
    for (int kk = 0; kk < 32; ++kk) {
      float a[8], bb[8];
      *(float4*)&a[0] = *(const float4*)&As[kk][to * 8];
      *(float4*)&a[4] = *(const float4*)&As[kk][to * 8 + 4];
      *(float4*)&bb[0] = *(const float4*)&Bs[kk][tn * 8];
      *(float4*)&bb[4] = *(const float4*)&Bs[kk][tn * 8 + 4];
#pragma unroll
      for (int i = 0; i < 8; ++i)
#pragma unroll
        for (int j = 0; j < 8; ++j) acc[i][j] += a[i] * bb[j];
    }
    __syncthreads();
  }
#pragma unroll
  for (int i = 0; i < 8; ++i) {
    float* dst = qkv + ((size_t)b * OO + o0 + to * 8 + i) * NN + n0 + tn * 8;
    float4 v0 = {acc[i][0], acc[i][1], acc[i][2], acc[i][3]};
    float4 v1 = {acc[i][4], acc[i][5], acc[i][6], acc[i][7]};
    *(float4*)dst = v0;
    *(float4*)(dst + 4) = v1;
  }
}

// ---------------- K2: per-channel BN scale/shift for qkv ----------------
__global__ __launch_bounds__(256) void k_qkv_stats(const float* __restrict__ qkv,
                                                   const float* __restrict__ gq,
                                                   const float* __restrict__ bq,
                                                   float* __restrict__ qs,
                                                   float* __restrict__ qh) {
  const int o = blockIdx.x;
  const int t = threadIdx.x;
  float s = 0.f, ss = 0.f;
  for (int b = 0; b < BB; ++b) {
    float v = qkv[((size_t)b * OO + o) * NN + t];
    s += v; ss += v * v;
  }
#pragma unroll
  for (int m = 1; m < 64; m <<= 1) { s += __shfl_xor(s, m); ss += __shfl_xor(ss, m); }
  __shared__ float rs[4], rss[4];
  int wv = t >> 6;
  if ((t & 63) == 0) { rs[wv] = s; rss[wv] = ss; }
  __syncthreads();
  if (t == 0) {
    s = rs[0] + rs[1] + rs[2] + rs[3];
    ss = rss[0] + rss[1] + rss[2] + rss[3];
    const float inv = 1.f / (float)(BB * NN);
    float m = s * inv;
    float var = ss * inv - m * m;
    float r = rsqrtf(var + 1e-5f);
    float sc = gq[o] * r;
    qs[o] = sc;
    qh[o] = bq[o] - m * sc;
  }
}

// ---------------- K3a: sliding-window correlation tables for rel ----------------
// W[term][c][cp][i] = sum_{u=i}^{i+255} relp[term*32+c][u] * relp[term*32+cp][u]
// R[term][c][i]     = sum_{u=i}^{i+255} relp[term*32+c][u]
// term 0 = qr rows (0..31), term 1 = kr rows (32..63)
__global__ __launch_bounds__(256) void k_wprep(const float* __restrict__ relp,
                                               float* __restrict__ W,
                                               float* __restrict__ R) {
  const int gid = blockIdx.x * 256 + threadIdx.x;  // 0..8191
  const int pid = gid >> 2;                        // pair 0..2047
  const int i0 = (gid & 3) * 64;
  const int term = pid >> 10, c = (pid >> 5) & 31, cp = pid & 31;
  const float* ra = relp + (term * 32 + c) * 512;
  const float* rb = relp + (term * 32 + cp) * 512;
  float w = 0.f;
  for (int u = i0; u < i0 + 256; ++u) w += ra[u] * rb[u];
  float* Wp = W + pid * 256;
  Wp[i0] = w;
  for (int i = i0 + 1; i < i0 + 64; ++i) {
    w += ra[i + 255] * rb[i + 255] - ra[i - 1] * rb[i - 1];
    Wp[i] = w;
  }
  if (cp == 0) {
    float s = 0.f;
    for (int u = i0; u < i0 + 256; ++u) s += ra[u];
    float* Rp = R + (term * 32 + c) * 256;
    Rp[i0] = s;
    for (int i = i0 + 1; i < i0 + 64; ++i) { s += ra[i + 255] - ra[i - 1]; Rp[i] = s; }
  }
}

// ---------------- K3b: algebraic BN stats for qk/qr/kr (replaces full pass1) ----
// Per block (b,g), thread t = i:
//   ss_qr = sum_i q(:,i)^T Wq(i) q(:,i)     (quadratic form; W coalesced over i)
//   ss_kr = same with k and Wk
//   ss_qk = sum_{c,c'} Gq[c,c'] Gk[c,c']    (Grams over i via LDS tile)
//   s_qr  = sum_{c,i} q * Rq ; s_kr analogous ; s_qk = sum_c (sum_i q)(sum_j k)
__global__ __launch_bounds__(256) void k_simstats(const float* __restrict__ qkv,
                                                  const float* __restrict__ Wbuf,
                                                  const float* __restrict__ Rbuf,
                                                  const float* __restrict__ qs,
                                                  const float* __restrict__ qh,
                                                  float* __restrict__ simacc) {
  __shared__ float sh[64 * 260];       // rows 0..31 = q, 32..63 = k, pitch 260
  __shared__ float qsum[4][32], ksum[4][32];
  const int b = blockIdx.x >> 3, g = blockIdx.x & 7;
  const int t = threadIdx.x;           // = i
  const int wv = t >> 6, ln = t & 63;

  float q[32], k[32];
#pragma unroll
  for (int c = 0; c < 32; ++c) {
    int oq = g * 128 + c;
    int ok = g * 128 + 32 + c;
    q[c] = qkv[((size_t)b * OO + oq) * NN + t] * qs[oq] + qh[oq];
    k[c] = qkv[((size_t)b * OO + ok) * NN + t] * qs[ok] + qh[ok];
    sh[c * 260 + t] = q[c];
    sh[(32 + c) * 260 + t] = k[c];
  }
  __syncthreads();

  // ---- qr / kr quadratic forms + mean terms ----
  float ss_qr = 0.f, ss_kr = 0.f, s_qr = 0.f, s_kr = 0.f;
  const float* Wq = Wbuf;
  const float* Wk = Wbuf + 1024 * 256;
#pragma unroll
  for (int c = 0; c < 32; ++c) {
    float qc = q[c], kc = k[c];
    s_qr += qc * Rbuf[c * 256 + t];
    s_kr += kc * Rbuf[(32 + c) * 256 + t];
    ss_qr += qc * qc * Wq[(c * 33) * 256 + t];
    ss_kr += kc * kc * Wk[(c * 33) * 256 + t];
    float qc2 = qc + qc, kc2 = kc + kc;
#pragma unroll
    for (int cp = c + 1; cp < 32; ++cp) {
      ss_qr += qc2 * q[cp] * Wq[(c * 32 + cp) * 256 + t];
      ss_kr += kc2 * k[cp] * Wk[(c * 32 + cp) * 256 + t];
    }
  }

  // ---- qk second moment via Grams: thread owns 4 ordered (c,cp) pairs ----
  float ss_qk = 0.f;
#pragma unroll
  for (int pp = 0; pp < 4; ++pp) {
    int p = t + 256 * pp;
    int c = p >> 5, cp = p & 31;
    const float* qa = &sh[c * 260];
    const float* qb = &sh[cp * 260];
    const float* ka = &sh[(32 + c) * 260];
    const float* kb = &sh[(32 + cp) * 260];
    float gq = 0.f, gk = 0.f;
#pragma unroll 4
    for (int i = 0; i < 256; i += 4) {
      float4 a = *(const float4*)&qa[i];
      float4 bq = *(const float4*)&qb[i];
      gq += a.x * bq.x + a.y * bq.y + a.z * bq.z + a.w * bq.w;
      float4 ak = *(const float4*)&ka[i];
      float4 bk = *(const float4*)&kb[i];
      gk += ak.x * bk.x + ak.y * bk.y + ak.z * bk.z + ak.w * bk.w;
    }
    ss_qk += gq * gk;
  }

  // ---- reduce the five scalars across the block (per-wave + atomics) ----
#pragma unroll
  for (int m = 1; m < 64; m <<= 1) {
    ss_qk += __shfl_xor(ss_qk, m);
    ss_qr += __shfl_xor(ss_qr, m);
    ss_kr += __shfl_xor(ss_kr, m);
    s_qr += __shfl_xor(s_qr, m);
    s_kr += __shfl_xor(s_kr, m);
  }
  if (ln == 0) {
    atomicAdd(&simacc[24 + g], ss_qk);
    atomicAdd(&simacc[24 + 8 + g], ss_qr * (F_QR * F_QR));
    atomicAdd(&simacc[24 + 16 + g], ss_kr * (F_KR * F_KR));
    atomicAdd(&simacc[8 + g], s_qr * F_QR);
    atomicAdd(&simacc[16 + g], s_kr * F_KR);
  }

  // ---- qk mean: sum_c (sum_i q_c)(sum_j k_c) ----
#pragma unroll
  for (int c = 0; c < 32; ++c) {
    float a = q[c], bb2 = k[c];
#pragma unroll
    for (int m = 1; m < 64; m <<= 1) { a += __shfl_xor(a, m); bb2 += __shfl_xor(bb2, m); }
    if (ln == 0) { qsum[wv][c] = a; ksum[wv][c] = bb2; }
  }
  __syncthreads();
  if (t < 32) {
    float a = qsum[0][t] + qsum[1][t] + qsum[2][t] + qsum[3][t];
    float bb2 = ksum[0][t] + ksum[1][t] + ksum[2][t] + ksum[3][t];
    qsum[0][t] = a * bb2;
  }
  __syncthreads();
  if (t == 0) {
    float s = 0.f;
#pragma unroll
    for (int c = 0; c < 32; ++c) s += qsum[0][c];
    atomicAdd(&simacc[g], s);
  }
}

// ---------------- finalize sim BN coefficients ----------------
__global__ void k_sim_finalize(const float* __restrict__ simacc,
                               const float* __restrict__ gs,
                               const float* __restrict__ bs,
                               float* __restrict__ simscale,
                               float* __restrict__ simshift) {
  const int t = threadIdx.x;
  __shared__ float sh[24];
  if (t < 24) {
    const float inv = 1.f / (64.f * 256.f * 256.f);
    float m = simacc[t] * inv;
    float var = simacc[24 + t] * inv - m * m;
    float a = gs[t] * rsqrtf(var + 1e-5f);
    simscale[t] = a;
    sh[t] = bs[t] - m * a;
  }
  __syncthreads();
  if (t < 8) simshift[t] = sh[t] + sh[8 + t] + sh[16 + t];
}

// ---------------- pass2: sim + softmax + sv/sve ----------------
__global__ __launch_bounds__(256) void k_pass2(const float* __restrict__ qkv,
                                               const float* __restrict__ relp,
                                               const float* __restrict__ qs,
                                               const float* __restrict__ qh,
                                               const float* __restrict__ simscale,
                                               const float* __restrict__ simshift,
                                               float* __restrict__ svbuf,
                                               float* __restrict__ svebuf) {
  __shared__ float qt[2048];
  __shared__ float kt[8192];  // reused as vt in phase B

  const int it = blockIdx.x, bg = blockIdx.y;
  const int b = bg >> 3, g = bg & 7, i0 = it * 64;
  const int t = threadIdx.x, rg = t >> 4, cg = t & 15;
  const float aQK = simscale[g];
  const float aQR = F_QR * simscale[8 + g];
  const float aKR = F_KR * simscale[16 + g];
  const float SH = simshift[g];

#pragma unroll
  for (int r = 0; r < 2; ++r) {
    int f = t + 256 * r;
    int row = f >> 4, c4 = f & 15;
    int o = g * 128 + row;
    float sc = qs[o], hh = qh[o];
    float4 v = *(const float4*)(qkv + ((size_t)b * OO + o) * NN + i0 + c4 * 4);
    *(float4*)&qt[row * 64 + c4 * 4] = bn4(v, sc, hh);
  }
#pragma unroll
  for (int r = 0; r < 8; ++r) {
    int f = t + 256 * r;
    int row = f >> 6, c4 = f & 63;
    int o = g * 128 + 32 + row;
    float sc = qs[o], hh = qh[o];
    float4 v = *(const float4*)(qkv + ((size_t)b * OO + o) * NN + c4 * 4);
    *(float4*)&kt[row * 256 + c4 * 4] = bn4(v, sc, hh);
  }
  __syncthreads();

  float p[4][4][4];
#pragma unroll
  for (int di = 0; di < 4; ++di)
#pragma unroll
    for (int q = 0; q < 4; ++q)
#pragma unroll
      for (int dj = 0; dj < 4; ++dj) p[di][q][dj] = 0.f;

  // unified logits loop: qk + qr + kr share the q4/k16 LDS loads
  for (int c = 0; c < 32; ++c) {
    float q4[4];
    *(float4*)q4 = *(const float4*)&qt[c * 64 + rg * 4];
    float k16[4][4];
#pragma unroll
    for (int q = 0; q < 4; ++q) *(float4*)k16[q] = *(const float4*)&kt[c * 256 + q * 64 + cg * 4];
    float q4a[4], q4r[4];
#pragma unroll
    for (int di = 0; di < 4; ++di) { q4a[di] = q4[di] * aQK; q4r[di] = q4[di] * aQR; }
    // qk
#pragma unroll
    for (int di = 0; di < 4; ++di)
#pragma unroll
      for (int q = 0; q < 4; ++q)
#pragma unroll
        for (int dj = 0; dj < 4; ++dj) p[di][q][dj] += q4a[di] * k16[q][dj];
    // qr
#pragma unroll
    for (int q = 0; q < 4; ++q) {
      const float* rp = relp + c * 512 + (i0 + rg * 4 - cg * 4 - 64 * q + 252);
      float rq[8];
      *(float4*)&rq[0] = *(const float4*)rp;
      *(float4*)&rq[4] = *(const float4*)(rp + 4);
#pragma unroll
      for (int di = 0; di < 4; ++di)
#pragma unroll
        for (int dj = 0; dj < 4; ++dj) p[di][q][dj] += q4r[di] * rq[di - dj + 3];
    }
    // kr (fold aKR into k16, which is dead after this)
#pragma unroll
    for (int q = 0; q < 4; ++q)
#pragma unroll
      for (int dj = 0; dj < 4; ++dj) k16[q][dj] *= aKR;
#pragma unroll
    for (int q = 0; q < 4; ++q) {
      const float* rp = relp + (32 + c) * 512 + (64 * q + cg * 4 - i0 - rg * 4 + 252);
      float rk[8];
      *(float4*)&rk[0] = *(const float4*)rp;
      *(float4*)&rk[4] = *(const float4*)(rp + 4);
#pragma unroll
      for (int di = 0; di < 4; ++di)
#pragma unroll
        for (int dj = 0; dj < 4; ++dj) p[di][q][dj] += k16[q][dj] * rk[dj - di + 3];
    }
  }

  // shift + softmax over j (16 cg lanes per row i)
#pragma unroll
  for (int di = 0; di < 4; ++di) {
    float m = -1e30f;
#pragma unroll
    for (int q = 0; q < 4; ++q)
#pragma unroll
      for (int dj = 0; dj < 4; ++dj) { p[di][q][dj] += SH; m = fmaxf(m, p[di][q][dj]); }
#pragma unroll
    for (int k = 1; k < 16; k <<= 1) m = fmaxf(m, __shfl_xor(m, k));
    float s = 0.f;
#pragma unroll
    for (int q = 0; q < 4; ++q)
#pragma unroll
      for (int dj = 0; dj < 4; ++dj) { p[di][q][dj] = __expf(p[di][q][dj] - m); s += p[di][q][dj]; }
#pragma unroll
    for (int k = 1; k < 16; k <<= 1) s += __shfl_xor(s, k);
    float invs = 1.f / s;
#pragma unroll
    for (int q = 0; q < 4; ++q)
#pragma unroll
      for (int dj = 0; dj < 4; ++dj) p[di][q][dj] *= invs;
  }
  __syncthreads();

  // phase B: sv and sve
  for (int chunk = 0; chunk < 2; ++chunk) {
#pragma unroll
    for (int r = 0; r < 8; ++r) {
      int f = t + 256 * r;
      int row = f >> 6, c4 = f & 63;
      int o = g * 128 + 64 + chunk * 32 + row;
      float sc = qs[o], hh = qh[o];
      float4 v = *(const float4*)(qkv + ((size_t)b * OO + o) * NN + c4 * 4);
      *(float4*)&kt[row * 256 + c4 * 4] = bn4(v, sc, hh);
    }
    __syncthreads();
    for (int c = 0; c < 32; ++c) {
      float v16[4][4];
#pragma unroll
      for (int q = 0; q < 4; ++q) *(float4*)v16[q] = *(const float4*)&kt[c * 256 + q * 64 + cg * 4];
      float sp[4], se[4];
#pragma unroll
      for (int di = 0; di < 4; ++di) {
        float s = 0.f;
#pragma unroll
        for (int q = 0; q < 4; ++q)
#pragma unroll
          for (int dj = 0; dj < 4; ++dj) s += p[di][q][dj] * v16[q][dj];
        sp[di] = s;
      }
      float rv[4][8];
#pragma unroll
      for (int q = 0; q < 4; ++q) {
        const float* rp = relp + (64 + chunk * 32 + c) * 512 + (i0 + rg * 4 - cg * 4 - 64 * q + 252);
        *(float4*)&rv[q][0] = *(const float4*)rp;
        *(float4*)&rv[q][4] = *(const float4*)(rp + 4);
      }
#pragma unroll
      for (int di = 0; di < 4; ++di) {
        float s = 0.f;
#pragma unroll
        for (int q = 0; q < 4; ++q)
#pragma unroll
          for (int dj = 0; dj < 4; ++dj) s += p[di][q][dj] * rv[q][di - dj + 3];
        se[di] = s;
      }
#pragma unroll
      for (int di = 0; di < 4; ++di)
#pragma unroll
        for (int k = 1; k < 16; k <<= 1) {
          sp[di] += __shfl_xor(sp[di], k);
          se[di] += __shfl_xor(se[di], k);
        }
      if (cg == 0) {
        float4 o1 = {sp[0], sp[1], sp[2], sp[3]};
        *(float4*)(svbuf + ((size_t)(b * 512 + g * 64 + chunk * 32 + c)) * NN + i0 + rg * 4) = o1;
        float4 o2 = {se[0] * F_SVE, se[1] * F_SVE, se[2] * F_SVE, se[3] * F_SVE};
        *(float4*)(svebuf + ((size_t)(b * 512 + g * 64 + chunk * 32 + c)) * NN + i0 + rg * 4) = o2;
      }
    }
    __syncthreads();
  }
}

// ---------------- K6: final BN stats over sv / sve ----------------
__global__ __launch_bounds__(256) void k_out_stats(const float* __restrict__ svbuf,
                                                   const float* __restrict__ svebuf,
                                                   const float* __restrict__ go,
                                                   const float* __restrict__ bo,
                                                   float* __restrict__ osc,
                                                   float* __restrict__ osh) {
  const int bid = blockIdx.x;
  const int arr = bid >> 9, pch = bid & 511;
  const float* buf = arr ? svebuf : svbuf;
  const int t = threadIdx.x;
  float s = 0.f, ss = 0.f;
  for (int b = 0; b < BB; ++b) {
    float v = buf[((size_t)b * 512 + pch) * NN + t];
    s += v; ss += v * v;
  }
#pragma unroll
  for (int m = 1; m < 64; m <<= 1) { s += __shfl_xor(s, m); ss += __shfl_xor(ss, m); }
  __shared__ float rs[4], rss[4];
  int wv = t >> 6;
  if ((t & 63) == 0) { rs[wv] = s; rss[wv] = ss; }
  __syncthreads();
  if (t == 0) {
    s = rs[0] + rs[1] + rs[2] + rs[3];
    ss = rss[0] + rss[1] + rss[2] + rss[3];
    const float inv = 1.f / 16384.f;
    float m = s * inv;
    float var = ss * inv - m * m;
    float r = rsqrtf(var + 1e-5f);
    int o = pch * 2 + arr;
    float sc = go[o] * r;
    osc[bid] = sc;
    osh[bid] = bo[o] - m * sc;
  }
}

// ---------------- K7: combine ----------------
__global__ __launch_bounds__(256) void k_final(const float* __restrict__ svbuf,
                                               const float* __restrict__ svebuf,
                                               const float* __restrict__ osc,
                                               const float* __restrict__ osh,
                                               float* __restrict__ out) {
  const size_t f = (size_t)blockIdx.x * 256 + threadIdx.x;  // float4 index
  const int pch = (int)((f >> 6) & 511);
  float4 a = ((const float4*)svbuf)[f];
  float4 e = ((const float4*)svebuf)[f];
  float s1 = osc[pch], h1 = osh[pch];
  float s2 = osc[512 + pch], h2 = osh[512 + pch];
  float hh = h1 + h2;
  float4 o;
  o.x = a.x * s1 + e.x * s2 + hh;
  o.y = a.y * s1 + e.y * s2 + hh;
  o.z = a.z * s1 + e.z * s2 + hh;
  o.w = a.w * s1 + e.w * s2 + hh;
  ((float4*)out)[f] = o;
}

extern "C" void kernel_launch(void* const* d_in, const int* in_sizes, int n_in,
                              void* d_out, int out_size, void* d_ws, size_t ws_size,
                              hipStream_t stream) {
  const float* x     = (const float*)d_in[0];
  const float* w     = (const float*)d_in[1];
  const float* rel   = (const float*)d_in[2];
  const float* g_qkv = (const float*)d_in[3];
  const float* b_qkv = (const float*)d_in[4];
  const float* g_sim = (const float*)d_in[5];
  const float* b_sim = (const float*)d_in[6];
  const float* g_out = (const float*)d_in[7];
  const float* b_out = (const float*)d_in[8];

  float* ws = (float*)d_ws;
  float* qkv      = ws;                       // 16,777,216
  float* sv       = qkv + 16777216;           // 8,388,608
  float* sve      = sv + 8388608;             // 8,388,608
  float* qs       = sve + 8388608;            // 1024
  float* qh       = qs + 1024;                // 1024
  float* simacc   = qh + 1024;                // 48
  float* simscale = simacc + 48;              // 24
  float* simshift = simscale + 24;            // 8
  float* osc      = simshift + 8;             // 1024
  float* osh      = osc + 1024;               // 1024

  // relp (128x512 padded rel copy) lives in d_out's tail: d_out is dead until
  // k_final fully overwrites it, and relp is last read in k_pass2.
  float* relp = (float*)d_out;                // 65536 floats of 8.39M

  // W/R sliding-window tables alias the sv buffer: they are fully consumed by
  // k_simstats, which completes before k_pass2 first writes sv.
  float* Wbuf = sv;                           // 524,288 floats (2 MB)
  float* Rbuf = sv + 524288;                  // 16,384 floats

  hipMemsetAsync(simacc, 0, 48 * sizeof(float), stream);

  k_relpad<<<128, 256, 0, stream>>>(rel, relp);
  k_wprep<<<32, 256, 0, stream>>>(relp, Wbuf, Rbuf);
  k_qkv_gemm<<<dim3(2, 8, 64), 256, 0, stream>>>(x, w, qkv);
  k_qkv_stats<<<1024, 256, 0, stream>>>(qkv, g_qkv, b_qkv, qs, qh);
  k_simstats<<<512, 256, 0, stream>>>(qkv, Wbuf, Rbuf, qs, qh, simacc);
  k_sim_finalize<<<1, 32, 0, stream>>>(simacc, g_sim, b_sim, simscale, simshift);
  k_pass2<<<dim3(4, 512), 256, 0, stream>>>(qkv, relp, qs, qh, simscale, simshift, sv, sve);
  k_out_stats<<<1024, 256, 0, stream>>>(sv, sve, g_out, b_out, osc, osh);
  k_final<<<8192, 256, 0, stream>>>(sv, sve, osc, osh, (float*)d_out);
}

// Round 4
// 876.320 us; speedup vs baseline: 1.7660x; 1.7660x over previous
//
#include <hip/hip_runtime.h>

#define NN 256
#define CC 512
#define OO 1024
#define BB 64

#define F_QR 0.1f
#define F_KR 0.1f
#define F_SVE 0.1f

__device__ inline float4 bn4(float4 v, float sc, float hh) {
  return make_float4(v.x * sc + hh, v.y * sc + hh, v.z * sc + hh, v.w * sc + hh);
}

// ---------------- K0: pad rel rows 511 -> 512 (enables aligned float4 rel loads)
__global__ void k_relpad(const float* __restrict__ rel, float* __restrict__ relp) {
  const int row = blockIdx.x;
  const int t = threadIdx.x;
  for (int u = t; u < 511; u += 256) relp[row * 512 + u] = rel[row * 511 + u];
  if (t == 0) relp[row * 512 + 511] = 0.f;
}

// ---------------- K1: qkv[b][o][n] = sum_c W[o][c] * x[b][n][c] ----------------
__global__ __launch_bounds__(256) void k_qkv_gemm(const float* __restrict__ x,
                                                  const float* __restrict__ w,
                                                  float* __restrict__ qkv) {
  const int b = blockIdx.z, ot = blockIdx.y, nt = blockIdx.x;
  const int o0 = ot * 128, n0 = nt * 128;
  __shared__ float As[32][132];
  __shared__ float Bs[32][132];
  const int t = threadIdx.x;
  const int to = t >> 4, tn = t & 15;
  float acc[8][8];
#pragma unroll
  for (int i = 0; i < 8; ++i)
#pragma unroll
    for (int j = 0; j < 8; ++j) acc[i][j] = 0.f;

  const float* wbase = w + (size_t)o0 * CC;
  const float* xbase = x + (size_t)b * NN * CC + (size_t)n0 * CC;

  for (int c0 = 0; c0 < CC; c0 += 32) {
#pragma unroll
    for (int r = 0; r < 4; ++r) {
      int f = t + 256 * r;
      int row = f >> 3, cq = f & 7;
      float4 w4 = *(const float4*)(wbase + (size_t)row * CC + c0 + cq * 4);
      As[cq * 4 + 0][row] = w4.x; As[cq * 4 + 1][row] = w4.y;
      As[cq * 4 + 2][row] = w4.z; As[cq * 4 + 3][row] = w4.w;
      float4 x4 = *(const float4*)(xbase + (size_t)row * CC + c0 + cq * 4);
      Bs[cq * 4 + 0][row] = x4.x; Bs[cq * 4 + 1][row] = x4.y;
      Bs[cq * 4 + 2][row] = x4.z; Bs[cq * 4 + 3][row] = x4.w;
    }
    __syncthreads();
#pragma unroll
    for (int kk = 0; kk < 32; ++kk) {
      float a[8], bb[8];
      *(float4*)&a[0] = *(const float4*)&As[kk][to * 8];
      *(float4*)&a[4] = *(const float4*)&As[kk][to * 8 + 4];
      *(float4*)&bb[0] = *(const float4*)&Bs[kk][tn * 8];
      *(float4*)&bb[4] = *(const float4*)&Bs[kk][tn * 8 + 4];
#pragma unroll
      for (int i = 0; i < 8; ++i)
#pragma unroll
        for (int j = 0; j < 8; ++j) acc[i][j] += a[i] * bb[j];
    }
    __syncthreads();
  }
#pragma unroll
  for (int i = 0; i < 8; ++i) {
    float* dst = qkv + ((size_t)b * OO + o0 + to * 8 + i) * NN + n0 + tn * 8;
    float4 v0 = {acc[i][0], acc[i][1], acc[i][2], acc[i][3]};
    float4 v1 = {acc[i][4], acc[i][5], acc[i][6], acc[i][7]};
    *(float4*)dst = v0;
    *(float4*)(dst + 4) = v1;
  }
}

// ---------------- K2: per-channel BN scale/shift for qkv ----------------
__global__ __launch_bounds__(256) void k_qkv_stats(const float* __restrict__ qkv,
                                                   const float* __restrict__ gq,
                                                   const float* __restrict__ bq,
                                                   float* __restrict__ qs,
                                                   float* __restrict__ qh) {
  const int o = blockIdx.x;
  const int t = threadIdx.x;
  float s = 0.f, ss = 0.f;
  for (int b = 0; b < BB; ++b) {
    float v = qkv[((size_t)b * OO + o) * NN + t];
    s += v; ss += v * v;
  }
#pragma unroll
  for (int m = 1; m < 64; m <<= 1) { s += __shfl_xor(s, m); ss += __shfl_xor(ss, m); }
  __shared__ float rs[4], rss[4];
  int wv = t >> 6;
  if ((t & 63) == 0) { rs[wv] = s; rss[wv] = ss; }
  __syncthreads();
  if (t == 0) {
    s = rs[0] + rs[1] + rs[2] + rs[3];
    ss = rss[0] + rss[1] + rss[2] + rss[3];
    const float inv = 1.f / (float)(BB * NN);
    float m = s * inv;
    float var = ss * inv - m * m;
    float r = rsqrtf(var + 1e-5f);
    float sc = gq[o] * r;
    qs[o] = sc;
    qh[o] = bq[o] - m * sc;
  }
}

// ---------------- K3a: sliding-window correlation tables for rel ----------------
// W[term][c][cp][i] = sum_{u=i}^{i+255} relp[term*32+c][u] * relp[term*32+cp][u]
// R[term][c][i]     = sum_{u=i}^{i+255} relp[term*32+c][u]
// term 0 = qr rows (0..31), term 1 = kr rows (32..63)
__global__ __launch_bounds__(256) void k_wprep(const float* __restrict__ relp,
                                               float* __restrict__ W,
                                               float* __restrict__ R) {
  const int gid = blockIdx.x * 256 + threadIdx.x;  // 0..8191
  const int pid = gid >> 2;                        // pair 0..2047
  const int i0 = (gid & 3) * 64;
  const int term = pid >> 10, c = (pid >> 5) & 31, cp = pid & 31;
  const float* ra = relp + (term * 32 + c) * 512;
  const float* rb = relp + (term * 32 + cp) * 512;
  float w = 0.f;
  for (int u = i0; u < i0 + 256; ++u) w += ra[u] * rb[u];
  float* Wp = W + pid * 256;
  Wp[i0] = w;
  for (int i = i0 + 1; i < i0 + 64; ++i) {
    w += ra[i + 255] * rb[i + 255] - ra[i - 1] * rb[i - 1];
    Wp[i] = w;
  }
  if (cp == 0) {
    float s = 0.f;
    for (int u = i0; u < i0 + 256; ++u) s += ra[u];
    float* Rp = R + (term * 32 + c) * 256;
    Rp[i0] = s;
    for (int i = i0 + 1; i < i0 + 64; ++i) { s += ra[i + 255] - ra[i - 1]; Rp[i] = s; }
  }
}

// ---------------- K3b: algebraic BN stats for qk/qr/kr ----------------
// Spill-free rework: q/k live ONLY in LDS (no register arrays), pair loop
// rolled (unroll 1 outer / 4 inner) so ~4 W loads in flight, small VGPR.
__global__ __launch_bounds__(256) void k_simstats(const float* __restrict__ qkv,
                                                  const float* __restrict__ Wbuf,
                                                  const float* __restrict__ Rbuf,
                                                  const float* __restrict__ qs,
                                                  const float* __restrict__ qh,
                                                  float* __restrict__ simacc) {
  __shared__ float sh[64 * 260];       // rows 0..31 = q, 32..63 = k, pitch 260
  __shared__ float qsum[4][32], ksum[4][32];
  const int b = blockIdx.x >> 3, g = blockIdx.x & 7;
  const int t = threadIdx.x;           // = i
  const int wv = t >> 6, ln = t & 63;

#pragma unroll 1
  for (int c = 0; c < 32; ++c) {
    int oq = g * 128 + c;
    int ok = g * 128 + 32 + c;
    sh[c * 260 + t] = qkv[((size_t)b * OO + oq) * NN + t] * qs[oq] + qh[oq];
    sh[(32 + c) * 260 + t] = qkv[((size_t)b * OO + ok) * NN + t] * qs[ok] + qh[ok];
  }
  __syncthreads();

  // ---- qr / kr quadratic forms + mean terms (rolled, LDS-sourced) ----
  float ss_qr = 0.f, ss_kr = 0.f, s_qr = 0.f, s_kr = 0.f;
  const float* Wq = Wbuf + t;
  const float* Wk = Wbuf + 1024 * 256 + t;
  const float* Rq = Rbuf + t;
#pragma unroll 1
  for (int c = 0; c < 32; ++c) {
    float qc = sh[c * 260 + t];
    float kc = sh[(32 + c) * 260 + t];
    s_qr += qc * Rq[c * 256];
    s_kr += kc * Rq[(32 + c) * 256];
    ss_qr += qc * qc * Wq[(c * 33) * 256];
    ss_kr += kc * kc * Wk[(c * 33) * 256];
    float qc2 = qc + qc, kc2 = kc + kc;
#pragma unroll 4
    for (int cp = c + 1; cp < 32; ++cp) {
      ss_qr += qc2 * sh[cp * 260 + t] * Wq[(c * 32 + cp) * 256];
      ss_kr += kc2 * sh[(32 + cp) * 260 + t] * Wk[(c * 32 + cp) * 256];
    }
  }

  // ---- qk second moment via Grams: thread owns 4 ordered (c,cp) pairs ----
  float ss_qk = 0.f;
#pragma unroll 1
  for (int pp = 0; pp < 4; ++pp) {
    int p = t + 256 * pp;
    int c = p >> 5, cp = p & 31;
    const float* qa = &sh[c * 260];
    const float* qb = &sh[cp * 260];
    const float* ka = &sh[(32 + c) * 260];
    const float* kb = &sh[(32 + cp) * 260];
    float gq = 0.f, gk = 0.f;
#pragma unroll 4
    for (int i = 0; i < 256; i += 4) {
      float4 a = *(const float4*)&qa[i];
      float4 bq = *(const float4*)&qb[i];
      gq += a.x * bq.x + a.y * bq.y + a.z * bq.z + a.w * bq.w;
      float4 ak = *(const float4*)&ka[i];
      float4 bk = *(const float4*)&kb[i];
      gk += ak.x * bk.x + ak.y * bk.y + ak.z * bk.z + ak.w * bk.w;
    }
    ss_qk += gq * gk;
  }

  // ---- reduce the five scalars across the block (per-wave + atomics) ----
#pragma unroll
  for (int m = 1; m < 64; m <<= 1) {
    ss_qk += __shfl_xor(ss_qk, m);
    ss_qr += __shfl_xor(ss_qr, m);
    ss_kr += __shfl_xor(ss_kr, m);
    s_qr += __shfl_xor(s_qr, m);
    s_kr += __shfl_xor(s_kr, m);
  }
  if (ln == 0) {
    atomicAdd(&simacc[24 + g], ss_qk);
    atomicAdd(&simacc[24 + 8 + g], ss_qr * (F_QR * F_QR));
    atomicAdd(&simacc[24 + 16 + g], ss_kr * (F_KR * F_KR));
    atomicAdd(&simacc[8 + g], s_qr * F_QR);
    atomicAdd(&simacc[16 + g], s_kr * F_KR);
  }

  // ---- qk mean: sum_c (sum_i q_c)(sum_j k_c), LDS-sourced ----
#pragma unroll 1
  for (int c = 0; c < 32; ++c) {
    float a = sh[c * 260 + t], bb2 = sh[(32 + c) * 260 + t];
#pragma unroll
    for (int m = 1; m < 64; m <<= 1) { a += __shfl_xor(a, m); bb2 += __shfl_xor(bb2, m); }
    if (ln == 0) { qsum[wv][c] = a; ksum[wv][c] = bb2; }
  }
  __syncthreads();
  if (t < 32) {
    float a = qsum[0][t] + qsum[1][t] + qsum[2][t] + qsum[3][t];
    float bb2 = ksum[0][t] + ksum[1][t] + ksum[2][t] + ksum[3][t];
    qsum[0][t] = a * bb2;
  }
  __syncthreads();
  if (t == 0) {
    float s = 0.f;
#pragma unroll
    for (int c = 0; c < 32; ++c) s += qsum[0][c];
    atomicAdd(&simacc[g], s);
  }
}

// ---------------- finalize sim BN coefficients ----------------
__global__ void k_sim_finalize(const float* __restrict__ simacc,
                               const float* __restrict__ gs,
                               const float* __restrict__ bs,
                               float* __restrict__ simscale,
                               float* __restrict__ simshift) {
  const int t = threadIdx.x;
  __shared__ float sh[24];
  if (t < 24) {
    const float inv = 1.f / (64.f * 256.f * 256.f);
    float m = simacc[t] * inv;
    float var = simacc[24 + t] * inv - m * m;
    float a = gs[t] * rsqrtf(var + 1e-5f);
    simscale[t] = a;
    sh[t] = bs[t] - m * a;
  }
  __syncthreads();
  if (t < 8) simshift[t] = sh[t] + sh[8 + t] + sh[16 + t];
}

// ---------------- pass2: sim + softmax + sv/sve ----------------
__global__ __launch_bounds__(256) void k_pass2(const float* __restrict__ qkv,
                                               const float* __restrict__ relp,
                                               const float* __restrict__ qs,
                                               const float* __restrict__ qh,
                                               const float* __restrict__ simscale,
                                               const float* __restrict__ simshift,
                                               float* __restrict__ svbuf,
                                               float* __restrict__ svebuf) {
  __shared__ float qt[2048];
  __shared__ float kt[8192];  // reused as vt in phase B

  const int it = blockIdx.x, bg = blockIdx.y;
  const int b = bg >> 3, g = bg & 7, i0 = it * 64;
  const int t = threadIdx.x, rg = t >> 4, cg = t & 15;
  const float aQK = simscale[g];
  const float aQR = F_QR * simscale[8 + g];
  const float aKR = F_KR * simscale[16 + g];
  const float SH = simshift[g];

#pragma unroll
  for (int r = 0; r < 2; ++r) {
    int f = t + 256 * r;
    int row = f >> 4, c4 = f & 15;
    int o = g * 128 + row;
    float sc = qs[o], hh = qh[o];
    float4 v = *(const float4*)(qkv + ((size_t)b * OO + o) * NN + i0 + c4 * 4);
    *(float4*)&qt[row * 64 + c4 * 4] = bn4(v, sc, hh);
  }
#pragma unroll
  for (int r = 0; r < 8; ++r) {
    int f = t + 256 * r;
    int row = f >> 6, c4 = f & 63;
    int o = g * 128 + 32 + row;
    float sc = qs[o], hh = qh[o];
    float4 v = *(const float4*)(qkv + ((size_t)b * OO + o) * NN + c4 * 4);
    *(float4*)&kt[row * 256 + c4 * 4] = bn4(v, sc, hh);
  }
  __syncthreads();

  float p[4][4][4];
#pragma unroll
  for (int di = 0; di < 4; ++di)
#pragma unroll
    for (int q = 0; q < 4; ++q)
#pragma unroll
      for (int dj = 0; dj < 4; ++dj) p[di][q][dj] = 0.f;

  // unified logits loop: qk + qr + kr share the q4/k16 LDS loads
  for (int c = 0; c < 32; ++c) {
    float q4[4];
    *(float4*)q4 = *(const float4*)&qt[c * 64 + rg * 4];
    float k16[4][4];
#pragma unroll
    for (int q = 0; q < 4; ++q) *(float4*)k16[q] = *(const float4*)&kt[c * 256 + q * 64 + cg * 4];
    float q4a[4], q4r[4];
#pragma unroll
    for (int di = 0; di < 4; ++di) { q4a[di] = q4[di] * aQK; q4r[di] = q4[di] * aQR; }
    // qk
#pragma unroll
    for (int di = 0; di < 4; ++di)
#pragma unroll
      for (int q = 0; q < 4; ++q)
#pragma unroll
        for (int dj = 0; dj < 4; ++dj) p[di][q][dj] += q4a[di] * k16[q][dj];
    // qr
#pragma unroll
    for (int q = 0; q < 4; ++q) {
      const float* rp = relp + c * 512 + (i0 + rg * 4 - cg * 4 - 64 * q + 252);
      float rq[8];
      *(float4*)&rq[0] = *(const float4*)rp;
      *(float4*)&rq[4] = *(const float4*)(rp + 4);
#pragma unroll
      for (int di = 0; di < 4; ++di)
#pragma unroll
        for (int dj = 0; dj < 4; ++dj) p[di][q][dj] += q4r[di] * rq[di - dj + 3];
    }
    // kr (fold aKR into k16, which is dead after this)
#pragma unroll
    for (int q = 0; q < 4; ++q)
#pragma unroll
      for (int dj = 0; dj < 4; ++dj) k16[q][dj] *= aKR;
#pragma unroll
    for (int q = 0; q < 4; ++q) {
      const float* rp = relp + (32 + c) * 512 + (64 * q + cg * 4 - i0 - rg * 4 + 252);
      float rk[8];
      *(float4*)&rk[0] = *(const float4*)rp;
      *(float4*)&rk[4] = *(const float4*)(rp + 4);
#pragma unroll
      for (int di = 0; di < 4; ++di)
#pragma unroll
        for (int dj = 0; dj < 4; ++dj) p[di][q][dj] += k16[q][dj] * rk[dj - di + 3];
    }
  }

  // shift + softmax over j (16 cg lanes per row i)
#pragma unroll
  for (int di = 0; di < 4; ++di) {
    float m = -1e30f;
#pragma unroll
    for (int q = 0; q < 4; ++q)
#pragma unroll
      for (int dj = 0; dj < 4; ++dj) { p[di][q][dj] += SH; m = fmaxf(m, p[di][q][dj]); }
#pragma unroll
    for (int k = 1; k < 16; k <<= 1) m = fmaxf(m, __shfl_xor(m, k));
    float s = 0.f;
#pragma unroll
    for (int q = 0; q < 4; ++q)
#pragma unroll
      for (int dj = 0; dj < 4; ++dj) { p[di][q][dj] = __expf(p[di][q][dj] - m); s += p[di][q][dj]; }
#pragma unroll
    for (int k = 1; k < 16; k <<= 1) s += __shfl_xor(s, k);
    float invs = 1.f / s;
#pragma unroll
    for (int q = 0; q < 4; ++q)
#pragma unroll
      for (int dj = 0; dj < 4; ++dj) p[di][q][dj] *= invs;
  }
  __syncthreads();

  // phase B: sv and sve
  for (int chunk = 0; chunk < 2; ++chunk) {
#pragma unroll
    for (int r = 0; r < 8; ++r) {
      int f = t + 256 * r;
      int row = f >> 6, c4 = f & 63;
      int o = g * 128 + 64 + chunk * 32 + row;
      float sc = qs[o], hh = qh[o];
      float4 v = *(const float4*)(qkv + ((size_t)b * OO + o) * NN + c4 * 4);
      *(float4*)&kt[row * 256 + c4 * 4] = bn4(v, sc, hh);
    }
    __syncthreads();
    for (int c = 0; c < 32; ++c) {
      float v16[4][4];
#pragma unroll
      for (int q = 0; q < 4; ++q) *(float4*)v16[q] = *(const float4*)&kt[c * 256 + q * 64 + cg * 4];
      float sp[4], se[4];
#pragma unroll
      for (int di = 0; di < 4; ++di) {
        float s = 0.f;
#pragma unroll
        for (int q = 0; q < 4; ++q)
#pragma unroll
          for (int dj = 0; dj < 4; ++dj) s += p[di][q][dj] * v16[q][dj];
        sp[di] = s;
      }
      float rv[4][8];
#pragma unroll
      for (int q = 0; q < 4; ++q) {
        const float* rp = relp + (64 + chunk * 32 + c) * 512 + (i0 + rg * 4 - cg * 4 - 64 * q + 252);
        *(float4*)&rv[q][0] = *(const float4*)rp;
        *(float4*)&rv[q][4] = *(const float4*)(rp + 4);
      }
#pragma unroll
      for (int di = 0; di < 4; ++di) {
        float s = 0.f;
#pragma unroll
        for (int q = 0; q < 4; ++q)
#pragma unroll
          for (int dj = 0; dj < 4; ++dj) s += p[di][q][dj] * rv[q][di - dj + 3];
        se[di] = s;
      }
#pragma unroll
      for (int di = 0; di < 4; ++di)
#pragma unroll
        for (int k = 1; k < 16; k <<= 1) {
          sp[di] += __shfl_xor(sp[di], k);
          se[di] += __shfl_xor(se[di], k);
        }
      if (cg == 0) {
        float4 o1 = {sp[0], sp[1], sp[2], sp[3]};
        *(float4*)(svbuf + ((size_t)(b * 512 + g * 64 + chunk * 32 + c)) * NN + i0 + rg * 4) = o1;
        float4 o2 = {se[0] * F_SVE, se[1] * F_SVE, se[2] * F_SVE, se[3] * F_SVE};
        *(float4*)(svebuf + ((size_t)(b * 512 + g * 64 + chunk * 32 + c)) * NN + i0 + rg * 4) = o2;
      }
    }
    __syncthreads();
  }
}

// ---------------- K6: final BN stats over sv / sve ----------------
__global__ __launch_bounds__(256) void k_out_stats(const float* __restrict__ svbuf,
                                                   const float* __restrict__ svebuf,
                                                   const float* __restrict__ go,
                                                   const float* __restrict__ bo,
                                                   float* __restrict__ osc,
                                                   float* __restrict__ osh) {
  const int bid = blockIdx.x;
  const int arr = bid >> 9, pch = bid & 511;
  const float* buf = arr ? svebuf : svbuf;
  const int t = threadIdx.x;
  float s = 0.f, ss = 0.f;
  for (int b = 0; b < BB; ++b) {
    float v = buf[((size_t)b * 512 + pch) * NN + t];
    s += v; ss += v * v;
  }
#pragma unroll
  for (int m = 1; m < 64; m <<= 1) { s += __shfl_xor(s, m); ss += __shfl_xor(ss, m); }
  __shared__ float rs[4], rss[4];
  int wv = t >> 6;
  if ((t & 63) == 0) { rs[wv] = s; rss[wv] = ss; }
  __syncthreads();
  if (t == 0) {
    s = rs[0] + rs[1] + rs[2] + rs[3];
    ss = rss[0] + rss[1] + rss[2] + rss[3];
    const float inv = 1.f / 16384.f;
    float m = s * inv;
    float var = ss * inv - m * m;
    float r = rsqrtf(var + 1e-5f);
    int o = pch * 2 + arr;
    float sc = go[o] * r;
    osc[bid] = sc;
    osh[bid] = bo[o] - m * sc;
  }
}

// ---------------- K7: combine ----------------
__global__ __launch_bounds__(256) void k_final(const float* __restrict__ svbuf,
                                               const float* __restrict__ svebuf,
                                               const float* __restrict__ osc,
                                               const float* __restrict__ osh,
                                               float* __restrict__ out) {
  const size_t f = (size_t)blockIdx.x * 256 + threadIdx.x;  // float4 index
  const int pch = (int)((f >> 6) & 511);
  float4 a = ((const float4*)svbuf)[f];
  float4 e = ((const float4*)svebuf)[f];
  float s1 = osc[pch], h1 = osh[pch];
  float s2 = osc[512 + pch], h2 = osh[512 + pch];
  float hh = h1 + h2;
  float4 o;
  o.x = a.x * s1 + e.x * s2 + hh;
  o.y = a.y * s1 + e.y * s2 + hh;
  o.z = a.z * s1 + e.z * s2 + hh;
  o.w = a.w * s1 + e.w * s2 + hh;
  ((float4*)out)[f] = o;
}

extern "C" void kernel_launch(void* const* d_in, const int* in_sizes, int n_in,
                              void* d_out, int out_size, void* d_ws, size_t ws_size,
                              hipStream_t stream) {
  const float* x     = (const float*)d_in[0];
  const float* w     = (const float*)d_in[1];
  const float* rel   = (const float*)d_in[2];
  const float* g_qkv = (const float*)d_in[3];
  const float* b_qkv = (const float*)d_in[4];
  const float* g_sim = (const float*)d_in[5];
  const float* b_sim = (const float*)d_in[6];
  const float* g_out = (const float*)d_in[7];
  const float* b_out = (const float*)d_in[8];

  float* ws = (float*)d_ws;
  float* qkv      = ws;                       // 16,777,216
  float* sv       = qkv + 16777216;           // 8,388,608
  float* sve      = sv + 8388608;             // 8,388,608
  float* qs       = sve + 8388608;            // 1024
  float* qh       = qs + 1024;                // 1024
  float* simacc   = qh + 1024;                // 48
  float* simscale = simacc + 48;              // 24
  float* simshift = simscale + 24;            // 8
  float* osc      = simshift + 8;             // 1024
  float* osh      = osc + 1024;               // 1024

  // relp (128x512 padded rel copy) lives in d_out's tail: d_out is dead until
  // k_final fully overwrites it, and relp is last read in k_pass2.
  float* relp = (float*)d_out;                // 65536 floats of 8.39M

  // W/R sliding-window tables alias the sv buffer: they are fully consumed by
  // k_simstats, which completes before k_pass2 first writes sv.
  float* Wbuf = sv;                           // 524,288 floats (2 MB)
  float* Rbuf = sv + 524288;                  // 16,384 floats

  hipMemsetAsync(simacc, 0, 48 * sizeof(float), stream);

  k_relpad<<<128, 256, 0, stream>>>(rel, relp);
  k_wprep<<<32, 256, 0, stream>>>(relp, Wbuf, Rbuf);
  k_qkv_gemm<<<dim3(2, 8, 64), 256, 0, stream>>>(x, w, qkv);
  k_qkv_stats<<<1024, 256, 0, stream>>>(qkv, g_qkv, b_qkv, qs, qh);
  k_simstats<<<512, 256, 0, stream>>>(qkv, Wbuf, Rbuf, qs, qh, simacc);
  k_sim_finalize<<<1, 32, 0, stream>>>(simacc, g_sim, b_sim, simscale, simshift);
  k_pass2<<<dim3(4, 512), 256, 0, stream>>>(qkv, relp, qs, qh, simscale, simshift, sv, sve);
  k_out_stats<<<1024, 256, 0, stream>>>(sv, sve, g_out, b_out, osc, osh);
  k_final<<<8192, 256, 0, stream>>>(sv, sve, osc, osh, (float*)d_out);
}

// Round 5
// 752.404 us; speedup vs baseline: 2.0568x; 1.1647x over previous
//
#include <hip/hip_runtime.h>

#define NN 256
#define CC 512
#define OO 1024
#define BB 64

#define F_QR 0.1f
#define F_KR 0.1f
#define F_SVE 0.1f

typedef __attribute__((ext_vector_type(8))) short bf16x8;
typedef __attribute__((ext_vector_type(4))) float f32x4;

__device__ inline float4 bn4(float4 v, float sc, float hh) {
  return make_float4(v.x * sc + hh, v.y * sc + hh, v.z * sc + hh, v.w * sc + hh);
}

__device__ inline unsigned short f2bf_rne(float f) {
  unsigned u = __float_as_uint(f);
  u += 0x7fffu + ((u >> 16) & 1u);
  return (unsigned short)(u >> 16);
}

// ---------------- K0: pad rel rows 511 -> 512 (enables aligned float4 rel loads)
__global__ void k_relpad(const float* __restrict__ rel, float* __restrict__ relp) {
  const int row = blockIdx.x;
  const int t = threadIdx.x;
  for (int u = t; u < 511; u += 256) relp[row * 512 + u] = rel[row * 511 + u];
  if (t == 0) relp[row * 512 + 511] = 0.f;
}

// ---------------- K1: qkv[b][o][n] = sum_c W[o][c] * x[b][n][c] ----------------
// Split-bf16 MFMA version: w = wh+wl, x = xh+xl (bf16 each);
// w*x ~= wh*xh + wh*xl + wl*xh (3 MFMAs, rel err ~2^-16, fp32 accumulate).
// Both A and B frags are loaded with the IDENTICAL (lane-group,reg)->k pattern
// from row-major [row][K] tiles, so the result is invariant to the HW's
// within-frag k-ordering (the permutation cancels between operands).
__global__ __launch_bounds__(256) void k_qkv_gemm(const float* __restrict__ x,
                                                  const float* __restrict__ w,
                                                  float* __restrict__ qkv) {
  __shared__ unsigned short Ah[128][40];  // KP=40 bf16 -> 80B row stride (16B aligned)
  __shared__ unsigned short Al[128][40];
  __shared__ unsigned short Bh[128][40];
  __shared__ unsigned short Bl[128][40];

  const int b = blockIdx.z, o0 = blockIdx.y * 128, n0 = blockIdx.x * 128;
  const int t = threadIdx.x;
  const int lane = t & 63, wid = t >> 6;
  const int wr = wid >> 1, wc = wid & 1;     // wave -> 64x64 quadrant
  const int frow = lane & 15;                // frag row/col within 16
  const int koff = (lane >> 4) * 8;          // frag k-offset (8 contiguous bf16)

  f32x4 acc[4][4];
#pragma unroll
  for (int i = 0; i < 4; ++i)
#pragma unroll
    for (int j = 0; j < 4; ++j) acc[i][j] = (f32x4){0.f, 0.f, 0.f, 0.f};

  const float* wb = w + (size_t)o0 * CC;
  const float* xb = x + (size_t)b * NN * CC + (size_t)n0 * CC;

  for (int c0 = 0; c0 < CC; c0 += 32) {
    if (c0) __syncthreads();
#pragma unroll
    for (int r = 0; r < 4; ++r) {
      int idx = t + 256 * r;
      int row = idx >> 3, c4 = idx & 7;
      float4 va = *(const float4*)(wb + (size_t)row * CC + c0 + c4 * 4);
      float4 vb = *(const float4*)(xb + (size_t)row * CC + c0 + c4 * 4);
      float af[4] = {va.x, va.y, va.z, va.w};
      float bf[4] = {vb.x, vb.y, vb.z, vb.w};
      unsigned short ah4[4], al4[4], bh4[4], bl4[4];
#pragma unroll
      for (int e = 0; e < 4; ++e) {
        unsigned ua = __float_as_uint(af[e]);
        unsigned short ha = (unsigned short)(ua >> 16);           // hi: truncate
        ah4[e] = ha;
        al4[e] = f2bf_rne(af[e] - __uint_as_float((unsigned)ha << 16));
        unsigned ub = __float_as_uint(bf[e]);
        unsigned short hb = (unsigned short)(ub >> 16);
        bh4[e] = hb;
        bl4[e] = f2bf_rne(bf[e] - __uint_as_float((unsigned)hb << 16));
      }
      *(short4*)&Ah[row][c4 * 4] = make_short4(ah4[0], ah4[1], ah4[2], ah4[3]);
      *(short4*)&Al[row][c4 * 4] = make_short4(al4[0], al4[1], al4[2], al4[3]);
      *(short4*)&Bh[row][c4 * 4] = make_short4(bh4[0], bh4[1], bh4[2], bh4[3]);
      *(short4*)&Bl[row][c4 * 4] = make_short4(bl4[0], bl4[1], bl4[2], bl4[3]);
    }
    __syncthreads();

    bf16x8 fah[4], fal[4], fbh[4], fbl[4];
#pragma unroll
    for (int mi = 0; mi < 4; ++mi) {
      int rr = wr * 64 + mi * 16 + frow;
      fah[mi] = *(const bf16x8*)&Ah[rr][koff];
      fal[mi] = *(const bf16x8*)&Al[rr][koff];
    }
#pragma unroll
    for (int nj = 0; nj < 4; ++nj) {
      int rr = wc * 64 + nj * 16 + frow;
      fbh[nj] = *(const bf16x8*)&Bh[rr][koff];
      fbl[nj] = *(const bf16x8*)&Bl[rr][koff];
    }
#pragma unroll
    for (int mi = 0; mi < 4; ++mi)
#pragma unroll
      for (int nj = 0; nj < 4; ++nj) {
        acc[mi][nj] = __builtin_amdgcn_mfma_f32_16x16x32_bf16(fah[mi], fbh[nj], acc[mi][nj], 0, 0, 0);
        acc[mi][nj] = __builtin_amdgcn_mfma_f32_16x16x32_bf16(fah[mi], fbl[nj], acc[mi][nj], 0, 0, 0);
        acc[mi][nj] = __builtin_amdgcn_mfma_f32_16x16x32_bf16(fal[mi], fbh[nj], acc[mi][nj], 0, 0, 0);
      }
  }

  // epilogue: C/D layout col=lane&15, row=(lane>>4)*4+reg  [m89-verified]
#pragma unroll
  for (int mi = 0; mi < 4; ++mi) {
    int orow = o0 + wr * 64 + mi * 16 + (lane >> 4) * 4;
#pragma unroll
    for (int nj = 0; nj < 4; ++nj) {
      int ncol = n0 + wc * 64 + nj * 16 + frow;
      float* dst = qkv + ((size_t)b * OO + orow) * NN + ncol;
#pragma unroll
      for (int j = 0; j < 4; ++j) dst[(size_t)j * NN] = acc[mi][nj][j];
    }
  }
}

// ---------------- K2: per-channel BN scale/shift for qkv ----------------
__global__ __launch_bounds__(256) void k_qkv_stats(const float* __restrict__ qkv,
                                                   const float* __restrict__ gq,
                                                   const float* __restrict__ bq,
                                                   float* __restrict__ qs,
                                                   float* __restrict__ qh) {
  const int o = blockIdx.x;
  const int t = threadIdx.x;
  float s = 0.f, ss = 0.f;
  for (int b = 0; b < BB; ++b) {
    float v = qkv[((size_t)b * OO + o) * NN + t];
    s += v; ss += v * v;
  }
#pragma unroll
  for (int m = 1; m < 64; m <<= 1) { s += __shfl_xor(s, m); ss += __shfl_xor(ss, m); }
  __shared__ float rs[4], rss[4];
  int wv = t >> 6;
  if ((t & 63) == 0) { rs[wv] = s; rss[wv] = ss; }
  __syncthreads();
  if (t == 0) {
    s = rs[0] + rs[1] + rs[2] + rs[3];
    ss = rss[0] + rss[1] + rss[2] + rss[3];
    const float inv = 1.f / (float)(BB * NN);
    float m = s * inv;
    float var = ss * inv - m * m;
    float r = rsqrtf(var + 1e-5f);
    float sc = gq[o] * r;
    qs[o] = sc;
    qh[o] = bq[o] - m * sc;
  }
}

// ---------------- K3a: sliding-window correlation tables for rel ----------------
__global__ __launch_bounds__(256) void k_wprep(const float* __restrict__ relp,
                                               float* __restrict__ W,
                                               float* __restrict__ R) {
  const int gid = blockIdx.x * 256 + threadIdx.x;  // 0..8191
  const int pid = gid >> 2;                        // pair 0..2047
  const int i0 = (gid & 3) * 64;
  const int term = pid >> 10, c = (pid >> 5) & 31, cp = pid & 31;
  const float* ra = relp + (term * 32 + c) * 512;
  const float* rb = relp + (term * 32 + cp) * 512;
  float w = 0.f;
  for (int u = i0; u < i0 + 256; ++u) w += ra[u] * rb[u];
  float* Wp = W + pid * 256;
  Wp[i0] = w;
  for (int i = i0 + 1; i < i0 + 64; ++i) {
    w += ra[i + 255] * rb[i + 255] - ra[i - 1] * rb[i - 1];
    Wp[i] = w;
  }
  if (cp == 0) {
    float s = 0.f;
    for (int u = i0; u < i0 + 256; ++u) s += ra[u];
    float* Rp = R + (term * 32 + c) * 256;
    Rp[i0] = s;
    for (int i = i0 + 1; i < i0 + 64; ++i) { s += ra[i + 255] - ra[i - 1]; Rp[i] = s; }
  }
}

// ---------------- K3b: algebraic BN stats for qk/qr/kr ----------------
__global__ __launch_bounds__(256) void k_simstats(const float* __restrict__ qkv,
                                                  const float* __restrict__ Wbuf,
                                                  const float* __restrict__ Rbuf,
                                                  const float* __restrict__ qs,
                                                  const float* __restrict__ qh,
                                                  float* __restrict__ simacc) {
  __shared__ float sh[64 * 260];       // rows 0..31 = q, 32..63 = k, pitch 260
  __shared__ float qsum[4][32], ksum[4][32];
  const int b = blockIdx.x >> 3, g = blockIdx.x & 7;
  const int t = threadIdx.x;           // = i
  const int wv = t >> 6, ln = t & 63;

#pragma unroll 1
  for (int c = 0; c < 32; ++c) {
    int oq = g * 128 + c;
    int ok = g * 128 + 32 + c;
    sh[c * 260 + t] = qkv[((size_t)b * OO + oq) * NN + t] * qs[oq] + qh[oq];
    sh[(32 + c) * 260 + t] = qkv[((size_t)b * OO + ok) * NN + t] * qs[ok] + qh[ok];
  }
  __syncthreads();

  float ss_qr = 0.f, ss_kr = 0.f, s_qr = 0.f, s_kr = 0.f;
  const float* Wq = Wbuf + t;
  const float* Wk = Wbuf + 1024 * 256 + t;
  const float* Rq = Rbuf + t;
#pragma unroll 1
  for (int c = 0; c < 32; ++c) {
    float qc = sh[c * 260 + t];
    float kc = sh[(32 + c) * 260 + t];
    s_qr += qc * Rq[c * 256];
    s_kr += kc * Rq[(32 + c) * 256];
    ss_qr += qc * qc * Wq[(c * 33) * 256];
    ss_kr += kc * kc * Wk[(c * 33) * 256];
    float qc2 = qc + qc, kc2 = kc + kc;
#pragma unroll 4
    for (int cp = c + 1; cp < 32; ++cp) {
      ss_qr += qc2 * sh[cp * 260 + t] * Wq[(c * 32 + cp) * 256];
      ss_kr += kc2 * sh[(32 + cp) * 260 + t] * Wk[(c * 32 + cp) * 256];
    }
  }

  float ss_qk = 0.f;
#pragma unroll 1
  for (int pp = 0; pp < 4; ++pp) {
    int p = t + 256 * pp;
    int c = p >> 5, cp = p & 31;
    const float* qa = &sh[c * 260];
    const float* qb = &sh[cp * 260];
    const float* ka = &sh[(32 + c) * 260];
    const float* kb = &sh[(32 + cp) * 260];
    float gq = 0.f, gk = 0.f;
#pragma unroll 4
    for (int i = 0; i < 256; i += 4) {
      float4 a = *(const float4*)&qa[i];
      float4 bq = *(const float4*)&qb[i];
      gq += a.x * bq.x + a.y * bq.y + a.z * bq.z + a.w * bq.w;
      float4 ak = *(const float4*)&ka[i];
      float4 bk = *(const float4*)&kb[i];
      gk += ak.x * bk.x + ak.y * bk.y + ak.z * bk.z + ak.w * bk.w;
    }
    ss_qk += gq * gk;
  }

#pragma unroll
  for (int m = 1; m < 64; m <<= 1) {
    ss_qk += __shfl_xor(ss_qk, m);
    ss_qr += __shfl_xor(ss_qr, m);
    ss_kr += __shfl_xor(ss_kr, m);
    s_qr += __shfl_xor(s_qr, m);
    s_kr += __shfl_xor(s_kr, m);
  }
  if (ln == 0) {
    atomicAdd(&simacc[24 + g], ss_qk);
    atomicAdd(&simacc[24 + 8 + g], ss_qr * (F_QR * F_QR));
    atomicAdd(&simacc[24 + 16 + g], ss_kr * (F_KR * F_KR));
    atomicAdd(&simacc[8 + g], s_qr * F_QR);
    atomicAdd(&simacc[16 + g], s_kr * F_KR);
  }

#pragma unroll 1
  for (int c = 0; c < 32; ++c) {
    float a = sh[c * 260 + t], bb2 = sh[(32 + c) * 260 + t];
#pragma unroll
    for (int m = 1; m < 64; m <<= 1) { a += __shfl_xor(a, m); bb2 += __shfl_xor(bb2, m); }
    if (ln == 0) { qsum[wv][c] = a; ksum[wv][c] = bb2; }
  }
  __syncthreads();
  if (t < 32) {
    float a = qsum[0][t] + qsum[1][t] + qsum[2][t] + qsum[3][t];
    float bb2 = ksum[0][t] + ksum[1][t] + ksum[2][t] + ksum[3][t];
    qsum[0][t] = a * bb2;
  }
  __syncthreads();
  if (t == 0) {
    float s = 0.f;
#pragma unroll
    for (int c = 0; c < 32; ++c) s += qsum[0][c];
    atomicAdd(&simacc[g], s);
  }
}

// ---------------- finalize sim BN coefficients ----------------
__global__ void k_sim_finalize(const float* __restrict__ simacc,
                               const float* __restrict__ gs,
                               const float* __restrict__ bs,
                               float* __restrict__ simscale,
                               float* __restrict__ simshift) {
  const int t = threadIdx.x;
  __shared__ float sh[24];
  if (t < 24) {
    const float inv = 1.f / (64.f * 256.f * 256.f);
    float m = simacc[t] * inv;
    float var = simacc[24 + t] * inv - m * m;
    float a = gs[t] * rsqrtf(var + 1e-5f);
    simscale[t] = a;
    sh[t] = bs[t] - m * a;
  }
  __syncthreads();
  if (t < 8) simshift[t] = sh[t] + sh[8 + t] + sh[16 + t];
}

// ---------------- pass2: sim + softmax + sv/sve ----------------
__global__ __launch_bounds__(256) void k_pass2(const float* __restrict__ qkv,
                                               const float* __restrict__ relp,
                                               const float* __restrict__ qs,
                                               const float* __restrict__ qh,
                                               const float* __restrict__ simscale,
                                               const float* __restrict__ simshift,
                                               float* __restrict__ svbuf,
                                               float* __restrict__ svebuf) {
  __shared__ float qt[2048];
  __shared__ float kt[8192];  // reused as vt in phase B

  const int it = blockIdx.x, bg = blockIdx.y;
  const int b = bg >> 3, g = bg & 7, i0 = it * 64;
  const int t = threadIdx.x, rg = t >> 4, cg = t & 15;
  const float aQK = simscale[g];
  const float aQR = F_QR * simscale[8 + g];
  const float aKR = F_KR * simscale[16 + g];
  const float SH = simshift[g];

#pragma unroll
  for (int r = 0; r < 2; ++r) {
    int f = t + 256 * r;
    int row = f >> 4, c4 = f & 15;
    int o = g * 128 + row;
    float sc = qs[o], hh = qh[o];
    float4 v = *(const float4*)(qkv + ((size_t)b * OO + o) * NN + i0 + c4 * 4);
    *(float4*)&qt[row * 64 + c4 * 4] = bn4(v, sc, hh);
  }
#pragma unroll
  for (int r = 0; r < 8; ++r) {
    int f = t + 256 * r;
    int row = f >> 6, c4 = f & 63;
    int o = g * 128 + 32 + row;
    float sc = qs[o], hh = qh[o];
    float4 v = *(const float4*)(qkv + ((size_t)b * OO + o) * NN + c4 * 4);
    *(float4*)&kt[row * 256 + c4 * 4] = bn4(v, sc, hh);
  }
  __syncthreads();

  float p[4][4][4];
#pragma unroll
  for (int di = 0; di < 4; ++di)
#pragma unroll
    for (int q = 0; q < 4; ++q)
#pragma unroll
      for (int dj = 0; dj < 4; ++dj) p[di][q][dj] = 0.f;

  for (int c = 0; c < 32; ++c) {
    float q4[4];
    *(float4*)q4 = *(const float4*)&qt[c * 64 + rg * 4];
    float k16[4][4];
#pragma unroll
    for (int q = 0; q < 4; ++q) *(float4*)k16[q] = *(const float4*)&kt[c * 256 + q * 64 + cg * 4];
    float q4a[4], q4r[4];
#pragma unroll
    for (int di = 0; di < 4; ++di) { q4a[di] = q4[di] * aQK; q4r[di] = q4[di] * aQR; }
#pragma unroll
    for (int di = 0; di < 4; ++di)
#pragma unroll
      for (int q = 0; q < 4; ++q)
#pragma unroll
        for (int dj = 0; dj < 4; ++dj) p[di][q][dj] += q4a[di] * k16[q][dj];
#pragma unroll
    for (int q = 0; q < 4; ++q) {
      const float* rp = relp + c * 512 + (i0 + rg * 4 - cg * 4 - 64 * q + 252);
      float rq[8];
      *(float4*)&rq[0] = *(const float4*)rp;
      *(float4*)&rq[4] = *(const float4*)(rp + 4);
#pragma unroll
      for (int di = 0; di < 4; ++di)
#pragma unroll
        for (int dj = 0; dj < 4; ++dj) p[di][q][dj] += q4r[di] * rq[di - dj + 3];
    }
#pragma unroll
    for (int q = 0; q < 4; ++q)
#pragma unroll
      for (int dj = 0; dj < 4; ++dj) k16[q][dj] *= aKR;
#pragma unroll
    for (int q = 0; q < 4; ++q) {
      const float* rp = relp + (32 + c) * 512 + (64 * q + cg * 4 - i0 - rg * 4 + 252);
      float rk[8];
      *(float4*)&rk[0] = *(const float4*)rp;
      *(float4*)&rk[4] = *(const float4*)(rp + 4);
#pragma unroll
      for (int di = 0; di < 4; ++di)
#pragma unroll
        for (int dj = 0; dj < 4; ++dj) p[di][q][dj] += k16[q][dj] * rk[dj - di + 3];
    }
  }

#pragma unroll
  for (int di = 0; di < 4; ++di) {
    float m = -1e30f;
#pragma unroll
    for (int q = 0; q < 4; ++q)
#pragma unroll
      for (int dj = 0; dj < 4; ++dj) { p[di][q][dj] += SH; m = fmaxf(m, p[di][q][dj]); }
#pragma unroll
    for (int k = 1; k < 16; k <<= 1) m = fmaxf(m, __shfl_xor(m, k));
    float s = 0.f;
#pragma unroll
    for (int q = 0; q < 4; ++q)
#pragma unroll
      for (int dj = 0; dj < 4; ++dj) { p[di][q][dj] = __expf(p[di][q][dj] - m); s += p[di][q][dj]; }
#pragma unroll
    for (int k = 1; k < 16; k <<= 1) s += __shfl_xor(s, k);
    float invs = 1.f / s;
#pragma unroll
    for (int q = 0; q < 4; ++q)
#pragma unroll
      for (int dj = 0; dj < 4; ++dj) p[di][q][dj] *= invs;
  }
  __syncthreads();

  for (int chunk = 0; chunk < 2; ++chunk) {
#pragma unroll
    for (int r = 0; r < 8; ++r) {
      int f = t + 256 * r;
      int row = f >> 6, c4 = f & 63;
      int o = g * 128 + 64 + chunk * 32 + row;
      float sc = qs[o], hh = qh[o];
      float4 v = *(const float4*)(qkv + ((size_t)b * OO + o) * NN + c4 * 4);
      *(float4*)&kt[row * 256 + c4 * 4] = bn4(v, sc, hh);
    }
    __syncthreads();
    for (int c = 0; c < 32; ++c) {
      float v16[4][4];
#pragma unroll
      for (int q = 0; q < 4; ++q) *(float4*)v16[q] = *(const float4*)&kt[c * 256 + q * 64 + cg * 4];
      float sp[4], se[4];
#pragma unroll
      for (int di = 0; di < 4; ++di) {
        float s = 0.f;
#pragma unroll
        for (int q = 0; q < 4; ++q)
#pragma unroll
          for (int dj = 0; dj < 4; ++dj) s += p[di][q][dj] * v16[q][dj];
        sp[di] = s;
      }
      float rv[4][8];
#pragma unroll
      for (int q = 0; q < 4; ++q) {
        const float* rp = relp + (64 + chunk * 32 + c) * 512 + (i0 + rg * 4 - cg * 4 - 64 * q + 252);
        *(float4*)&rv[q][0] = *(const float4*)rp;
        *(float4*)&rv[q][4] = *(const float4*)(rp + 4);
      }
#pragma unroll
      for (int di = 0; di < 4; ++di) {
        float s = 0.f;
#pragma unroll
        for (int q = 0; q < 4; ++q)
#pragma unroll
          for (int dj = 0; dj < 4; ++dj) s += p[di][q][dj] * rv[q][di - dj + 3];
        se[di] = s;
      }
#pragma unroll
      for (int di = 0; di < 4; ++di)
#pragma unroll
        for (int k = 1; k < 16; k <<= 1) {
          sp[di] += __shfl_xor(sp[di], k);
          se[di] += __shfl_xor(se[di], k);
        }
      if (cg == 0) {
        float4 o1 = {sp[0], sp[1], sp[2], sp[3]};
        *(float4*)(svbuf + ((size_t)(b * 512 + g * 64 + chunk * 32 + c)) * NN + i0 + rg * 4) = o1;
        float4 o2 = {se[0] * F_SVE, se[1] * F_SVE, se[2] * F_SVE, se[3] * F_SVE};
        *(float4*)(svebuf + ((size_t)(b * 512 + g * 64 + chunk * 32 + c)) * NN + i0 + rg * 4) = o2;
      }
    }
    __syncthreads();
  }
}

// ---------------- K6: final BN stats over sv / sve ----------------
__global__ __launch_bounds__(256) void k_out_stats(const float* __restrict__ svbuf,
                                                   const float* __restrict__ svebuf,
                                                   const float* __restrict__ go,
                                                   const float* __restrict__ bo,
                                                   float* __restrict__ osc,
                                                   float* __restrict__ osh) {
  const int bid = blockIdx.x;
  const int arr = bid >> 9, pch = bid & 511;
  const float* buf = arr ? svebuf : svbuf;
  const int t = threadIdx.x;
  float s = 0.f, ss = 0.f;
  for (int b = 0; b < BB; ++b) {
    float v = buf[((size_t)b * 512 + pch) * NN + t];
    s += v; ss += v * v;
  }
#pragma unroll
  for (int m = 1; m < 64; m <<= 1) { s += __shfl_xor(s, m); ss += __shfl_xor(ss, m); }
  __shared__ float rs[4], rss[4];
  int wv = t >> 6;
  if ((t & 63) == 0) { rs[wv] = s; rss[wv] = ss; }
  __syncthreads();
  if (t == 0) {
    s = rs[0] + rs[1] + rs[2] + rs[3];
    ss = rss[0] + rss[1] + rss[2] + rss[3];
    const float inv = 1.f / 16384.f;
    float m = s * inv;
    float var = ss * inv - m * m;
    float r = rsqrtf(var + 1e-5f);
    int o = pch * 2 + arr;
    float sc = go[o] * r;
    osc[bid] = sc;
    osh[bid] = bo[o] - m * sc;
  }
}

// ---------------- K7: combine ----------------
__global__ __launch_bounds__(256) void k_final(const float* __restrict__ svbuf,
                                               const float* __restrict__ svebuf,
                                               const float* __restrict__ osc,
                                               const float* __restrict__ osh,
                                               float* __restrict__ out) {
  const size_t f = (size_t)blockIdx.x * 256 + threadIdx.x;  // float4 index
  const int pch = (int)((f >> 6) & 511);
  float4 a = ((const float4*)svbuf)[f];
  float4 e = ((const float4*)svebuf)[f];
  float s1 = osc[pch], h1 = osh[pch];
  float s2 = osc[512 + pch], h2 = osh[512 + pch];
  float hh = h1 + h2;
  float4 o;
  o.x = a.x * s1 + e.x * s2 + hh;
  o.y = a.y * s1 + e.y * s2 + hh;
  o.z = a.z * s1 + e.z * s2 + hh;
  o.w = a.w * s1 + e.w * s2 + hh;
  ((float4*)out)[f] = o;
}

extern "C" void kernel_launch(void* const* d_in, const int* in_sizes, int n_in,
                              void* d_out, int out_size, void* d_ws, size_t ws_size,
                              hipStream_t stream) {
  const float* x     = (const float*)d_in[0];
  const float* w     = (const float*)d_in[1];
  const float* rel   = (const float*)d_in[2];
  const float* g_qkv = (const float*)d_in[3];
  const float* b_qkv = (const float*)d_in[4];
  const float* g_sim = (const float*)d_in[5];
  const float* b_sim = (const float*)d_in[6];
  const float* g_out = (const float*)d_in[7];
  const float* b_out = (const float*)d_in[8];

  float* ws = (float*)d_ws;
  float* qkv      = ws;                       // 16,777,216
  float* sv       = qkv + 16777216;           // 8,388,608
  float* sve      = sv + 8388608;             // 8,388,608
  float* qs       = sve + 8388608;            // 1024
  float* qh       = qs + 1024;                // 1024
  float* simacc   = qh + 1024;                // 48
  float* simscale = simacc + 48;              // 24
  float* simshift = simscale + 24;            // 8
  float* osc      = simshift + 8;             // 1024
  float* osh      = osc + 1024;               // 1024

  // relp (128x512 padded rel copy) lives in d_out's tail: d_out is dead until
  // k_final fully overwrites it, and relp is last read in k_pass2.
  float* relp = (float*)d_out;                // 65536 floats of 8.39M

  // W/R sliding-window tables alias the sv buffer: they are fully consumed by
  // k_simstats, which completes before k_pass2 first writes sv.
  float* Wbuf = sv;                           // 524,288 floats (2 MB)
  float* Rbuf = sv + 524288;                  // 16,384 floats

  hipMemsetAsync(simacc, 0, 48 * sizeof(float), stream);

  k_relpad<<<128, 256, 0, stream>>>(rel, relp);
  k_wprep<<<32, 256, 0, stream>>>(relp, Wbuf, Rbuf);
  k_qkv_gemm<<<dim3(2, 8, 64), 256, 0, stream>>>(x, w, qkv);
  k_qkv_stats<<<1024, 256, 0, stream>>>(qkv, g_qkv, b_qkv, qs, qh);
  k_simstats<<<512, 256, 0, stream>>>(qkv, Wbuf, Rbuf, qs, qh, simacc);
  k_sim_finalize<<<1, 32, 0, stream>>>(simacc, g_sim, b_sim, simscale, simshift);
  k_pass2<<<dim3(4, 512), 256, 0, stream>>>(qkv, relp, qs, qh, simscale, simshift, sv, sve);
  k_out_stats<<<1024, 256, 0, stream>>>(sv, sve, g_out, b_out, osc, osh);
  k_final<<<8192, 256, 0, stream>>>(sv, sve, osc, osh, (float*)d_out);
}

// Round 6
// 613.362 us; speedup vs baseline: 2.5231x; 1.2267x over previous
//
#include <hip/hip_runtime.h>

#define NN 256
#define CC 512
#define OO 1024
#define BB 64

#define F_QR 0.1f
#define F_KR 0.1f
#define F_SVE 0.1f

typedef __attribute__((ext_vector_type(8))) short bf16x8;
typedef __attribute__((ext_vector_type(4))) float f32x4;

__device__ inline float4 bn4(float4 v, float sc, float hh) {
  return make_float4(v.x * sc + hh, v.y * sc + hh, v.z * sc + hh, v.w * sc + hh);
}

__device__ inline unsigned short f2bf_rne(float f) {
  unsigned u = __float_as_uint(f);
  u += 0x7fffu + ((u >> 16) & 1u);
  return (unsigned short)(u >> 16);
}

__device__ inline float bf2f(unsigned short h) {
  return __uint_as_float((unsigned)h << 16);
}

// ---------------- K0: pad rel rows 511 -> 512 ----------------
__global__ void k_relpad(const float* __restrict__ rel, float* __restrict__ relp) {
  const int row = blockIdx.x;
  const int t = threadIdx.x;
  for (int u = t; u < 511; u += 256) relp[row * 512 + u] = rel[row * 511 + u];
  if (t == 0) relp[row * 512 + 511] = 0.f;
}

// ---------------- K1: qkv GEMM (split-bf16 MFMA, verified round 5) ----------------
__global__ __launch_bounds__(256) void k_qkv_gemm(const float* __restrict__ x,
                                                  const float* __restrict__ w,
                                                  float* __restrict__ qkv) {
  __shared__ unsigned short Ah[128][40];
  __shared__ unsigned short Al[128][40];
  __shared__ unsigned short Bh[128][40];
  __shared__ unsigned short Bl[128][40];

  const int b = blockIdx.z, o0 = blockIdx.y * 128, n0 = blockIdx.x * 128;
  const int t = threadIdx.x;
  const int lane = t & 63, wid = t >> 6;
  const int wr = wid >> 1, wc = wid & 1;
  const int frow = lane & 15;
  const int koff = (lane >> 4) * 8;

  f32x4 acc[4][4];
#pragma unroll
  for (int i = 0; i < 4; ++i)
#pragma unroll
    for (int j = 0; j < 4; ++j) acc[i][j] = (f32x4){0.f, 0.f, 0.f, 0.f};

  const float* wb = w + (size_t)o0 * CC;
  const float* xb = x + (size_t)b * NN * CC + (size_t)n0 * CC;

  for (int c0 = 0; c0 < CC; c0 += 32) {
    if (c0) __syncthreads();
#pragma unroll
    for (int r = 0; r < 4; ++r) {
      int idx = t + 256 * r;
      int row = idx >> 3, c4 = idx & 7;
      float4 va = *(const float4*)(wb + (size_t)row * CC + c0 + c4 * 4);
      float4 vb = *(const float4*)(xb + (size_t)row * CC + c0 + c4 * 4);
      float af[4] = {va.x, va.y, va.z, va.w};
      float bf[4] = {vb.x, vb.y, vb.z, vb.w};
      unsigned short ah4[4], al4[4], bh4[4], bl4[4];
#pragma unroll
      for (int e = 0; e < 4; ++e) {
        unsigned ua = __float_as_uint(af[e]);
        unsigned short ha = (unsigned short)(ua >> 16);
        ah4[e] = ha;
        al4[e] = f2bf_rne(af[e] - bf2f(ha));
        unsigned ub = __float_as_uint(bf[e]);
        unsigned short hb = (unsigned short)(ub >> 16);
        bh4[e] = hb;
        bl4[e] = f2bf_rne(bf[e] - bf2f(hb));
      }
      *(short4*)&Ah[row][c4 * 4] = make_short4(ah4[0], ah4[1], ah4[2], ah4[3]);
      *(short4*)&Al[row][c4 * 4] = make_short4(al4[0], al4[1], al4[2], al4[3]);
      *(short4*)&Bh[row][c4 * 4] = make_short4(bh4[0], bh4[1], bh4[2], bh4[3]);
      *(short4*)&Bl[row][c4 * 4] = make_short4(bl4[0], bl4[1], bl4[2], bl4[3]);
    }
    __syncthreads();

    bf16x8 fah[4], fal[4], fbh[4], fbl[4];
#pragma unroll
    for (int mi = 0; mi < 4; ++mi) {
      int rr = wr * 64 + mi * 16 + frow;
      fah[mi] = *(const bf16x8*)&Ah[rr][koff];
      fal[mi] = *(const bf16x8*)&Al[rr][koff];
    }
#pragma unroll
    for (int nj = 0; nj < 4; ++nj) {
      int rr = wc * 64 + nj * 16 + frow;
      fbh[nj] = *(const bf16x8*)&Bh[rr][koff];
      fbl[nj] = *(const bf16x8*)&Bl[rr][koff];
    }
#pragma unroll
    for (int mi = 0; mi < 4; ++mi)
#pragma unroll
      for (int nj = 0; nj < 4; ++nj) {
        acc[mi][nj] = __builtin_amdgcn_mfma_f32_16x16x32_bf16(fah[mi], fbh[nj], acc[mi][nj], 0, 0, 0);
        acc[mi][nj] = __builtin_amdgcn_mfma_f32_16x16x32_bf16(fah[mi], fbl[nj], acc[mi][nj], 0, 0, 0);
        acc[mi][nj] = __builtin_amdgcn_mfma_f32_16x16x32_bf16(fal[mi], fbh[nj], acc[mi][nj], 0, 0, 0);
      }
  }

#pragma unroll
  for (int mi = 0; mi < 4; ++mi) {
    int orow = o0 + wr * 64 + mi * 16 + (lane >> 4) * 4;
#pragma unroll
    for (int nj = 0; nj < 4; ++nj) {
      int ncol = n0 + wc * 64 + nj * 16 + frow;
      float* dst = qkv + ((size_t)b * OO + orow) * NN + ncol;
#pragma unroll
      for (int j = 0; j < 4; ++j) dst[(size_t)j * NN] = acc[mi][nj][j];
    }
  }
}

// ---------------- K2: per-channel BN scale/shift for qkv ----------------
__global__ __launch_bounds__(256) void k_qkv_stats(const float* __restrict__ qkv,
                                                   const float* __restrict__ gq,
                                                   const float* __restrict__ bq,
                                                   float* __restrict__ qs,
                                                   float* __restrict__ qh) {
  const int o = blockIdx.x;
  const int t = threadIdx.x;
  float s = 0.f, ss = 0.f;
  for (int b = 0; b < BB; ++b) {
    float v = qkv[((size_t)b * OO + o) * NN + t];
    s += v; ss += v * v;
  }
#pragma unroll
  for (int m = 1; m < 64; m <<= 1) { s += __shfl_xor(s, m); ss += __shfl_xor(ss, m); }
  __shared__ float rs[4], rss[4];
  int wv = t >> 6;
  if ((t & 63) == 0) { rs[wv] = s; rss[wv] = ss; }
  __syncthreads();
  if (t == 0) {
    s = rs[0] + rs[1] + rs[2] + rs[3];
    ss = rss[0] + rss[1] + rss[2] + rss[3];
    const float inv = 1.f / (float)(BB * NN);
    float m = s * inv;
    float var = ss * inv - m * m;
    float r = rsqrtf(var + 1e-5f);
    float sc = gq[o] * r;
    qs[o] = sc;
    qh[o] = bq[o] - m * sc;
  }
}

// ---------------- K3a: sliding-window correlation tables for rel ----------------
__global__ __launch_bounds__(256) void k_wprep(const float* __restrict__ relp,
                                               float* __restrict__ W,
                                               float* __restrict__ R) {
  const int gid = blockIdx.x * 256 + threadIdx.x;
  const int pid = gid >> 2;
  const int i0 = (gid & 3) * 64;
  const int term = pid >> 10, c = (pid >> 5) & 31, cp = pid & 31;
  const float* ra = relp + (term * 32 + c) * 512;
  const float* rb = relp + (term * 32 + cp) * 512;
  float w = 0.f;
  for (int u = i0; u < i0 + 256; ++u) w += ra[u] * rb[u];
  float* Wp = W + pid * 256;
  Wp[i0] = w;
  for (int i = i0 + 1; i < i0 + 64; ++i) {
    w += ra[i + 255] * rb[i + 255] - ra[i - 1] * rb[i - 1];
    Wp[i] = w;
  }
  if (cp == 0) {
    float s = 0.f;
    for (int u = i0; u < i0 + 256; ++u) s += ra[u];
    float* Rp = R + (term * 32 + c) * 256;
    Rp[i0] = s;
    for (int i = i0 + 1; i < i0 + 64; ++i) { s += ra[i + 255] - ra[i - 1]; Rp[i] = s; }
  }
}

// ---------------- K3b: algebraic BN stats for qk/qr/kr ----------------
__global__ __launch_bounds__(256) void k_simstats(const float* __restrict__ qkv,
                                                  const float* __restrict__ Wbuf,
                                                  const float* __restrict__ Rbuf,
                                                  const float* __restrict__ qs,
                                                  const float* __restrict__ qh,
                                                  float* __restrict__ simacc) {
  __shared__ float sh[64 * 260];
  __shared__ float qsum[4][32], ksum[4][32];
  const int b = blockIdx.x >> 3, g = blockIdx.x & 7;
  const int t = threadIdx.x;
  const int wv = t >> 6, ln = t & 63;

#pragma unroll 1
  for (int c = 0; c < 32; ++c) {
    int oq = g * 128 + c;
    int ok = g * 128 + 32 + c;
    sh[c * 260 + t] = qkv[((size_t)b * OO + oq) * NN + t] * qs[oq] + qh[oq];
    sh[(32 + c) * 260 + t] = qkv[((size_t)b * OO + ok) * NN + t] * qs[ok] + qh[ok];
  }
  __syncthreads();

  float ss_qr = 0.f, ss_kr = 0.f, s_qr = 0.f, s_kr = 0.f;
  const float* Wq = Wbuf + t;
  const float* Wk = Wbuf + 1024 * 256 + t;
  const float* Rq = Rbuf + t;
#pragma unroll 1
  for (int c = 0; c < 32; ++c) {
    float qc = sh[c * 260 + t];
    float kc = sh[(32 + c) * 260 + t];
    s_qr += qc * Rq[c * 256];
    s_kr += kc * Rq[(32 + c) * 256];
    ss_qr += qc * qc * Wq[(c * 33) * 256];
    ss_kr += kc * kc * Wk[(c * 33) * 256];
    float qc2 = qc + qc, kc2 = kc + kc;
#pragma unroll 4
    for (int cp = c + 1; cp < 32; ++cp) {
      ss_qr += qc2 * sh[cp * 260 + t] * Wq[(c * 32 + cp) * 256];
      ss_kr += kc2 * sh[(32 + cp) * 260 + t] * Wk[(c * 32 + cp) * 256];
    }
  }

  float ss_qk = 0.f;
#pragma unroll 1
  for (int pp = 0; pp < 4; ++pp) {
    int p = t + 256 * pp;
    int c = p >> 5, cp = p & 31;
    const float* qa = &sh[c * 260];
    const float* qb = &sh[cp * 260];
    const float* ka = &sh[(32 + c) * 260];
    const float* kb = &sh[(32 + cp) * 260];
    float gq = 0.f, gk = 0.f;
#pragma unroll 4
    for (int i = 0; i < 256; i += 4) {
      float4 a = *(const float4*)&qa[i];
      float4 bq = *(const float4*)&qb[i];
      gq += a.x * bq.x + a.y * bq.y + a.z * bq.z + a.w * bq.w;
      float4 ak = *(const float4*)&ka[i];
      float4 bk = *(const float4*)&kb[i];
      gk += ak.x * bk.x + ak.y * bk.y + ak.z * bk.z + ak.w * bk.w;
    }
    ss_qk += gq * gk;
  }

#pragma unroll
  for (int m = 1; m < 64; m <<= 1) {
    ss_qk += __shfl_xor(ss_qk, m);
    ss_qr += __shfl_xor(ss_qr, m);
    ss_kr += __shfl_xor(ss_kr, m);
    s_qr += __shfl_xor(s_qr, m);
    s_kr += __shfl_xor(s_kr, m);
  }
  if (ln == 0) {
    atomicAdd(&simacc[24 + g], ss_qk);
    atomicAdd(&simacc[24 + 8 + g], ss_qr * (F_QR * F_QR));
    atomicAdd(&simacc[24 + 16 + g], ss_kr * (F_KR * F_KR));
    atomicAdd(&simacc[8 + g], s_qr * F_QR);
    atomicAdd(&simacc[16 + g], s_kr * F_KR);
  }

#pragma unroll 1
  for (int c = 0; c < 32; ++c) {
    float a = sh[c * 260 + t], bb2 = sh[(32 + c) * 260 + t];
#pragma unroll
    for (int m = 1; m < 64; m <<= 1) { a += __shfl_xor(a, m); bb2 += __shfl_xor(bb2, m); }
    if (ln == 0) { qsum[wv][c] = a; ksum[wv][c] = bb2; }
  }
  __syncthreads();
  if (t < 32) {
    float a = qsum[0][t] + qsum[1][t] + qsum[2][t] + qsum[3][t];
    float bb2 = ksum[0][t] + ksum[1][t] + ksum[2][t] + ksum[3][t];
    qsum[0][t] = a * bb2;
  }
  __syncthreads();
  if (t == 0) {
    float s = 0.f;
#pragma unroll
    for (int c = 0; c < 32; ++c) s += qsum[0][c];
    atomicAdd(&simacc[g], s);
  }
}

// ---------------- finalize sim BN coefficients ----------------
__global__ void k_sim_finalize(const float* __restrict__ simacc,
                               const float* __restrict__ gs,
                               const float* __restrict__ bs,
                               float* __restrict__ simscale,
                               float* __restrict__ simshift) {
  const int t = threadIdx.x;
  __shared__ float sh[24];
  if (t < 24) {
    const float inv = 1.f / (64.f * 256.f * 256.f);
    float m = simacc[t] * inv;
    float var = simacc[24 + t] * inv - m * m;
    float a = gs[t] * rsqrtf(var + 1e-5f);
    simscale[t] = a;
    sh[t] = bs[t] - m * a;
  }
  __syncthreads();
  if (t < 8) simshift[t] = sh[t] + sh[8 + t] + sh[16 + t];
}

// ---------------- pass2: all-MFMA sim + softmax + sv/sve ----------------
// LDS regions (dynamic, 147456 B), time-phased:
//  MG_OFF  0      (40960): Mq[64][320]bf16 -> G[256][80]bf16 -> Ps[64][320]bf16
//  KH_OFF  40960  (16384): Kh[256][32]          | RV_OFF 40960 (40960): Rv[64][320] (phase B)
//  KL_OFF  57344  (16384): Kl[256][32]
//  RST_OFF 73728  (20480): Rq/Rk[320][32] (transposed)
//  VB_OFF  81920  (32768): Vb[64][256] (phase B)
//  QH_OFF  114688 (4096), QL_OFF 118784 (4096)  | PF_OFF 114688 (32768): Pf[64][256] (phase B)
#define MG_OFF   0
#define KH_OFF   40960
#define KL_OFF   57344
#define RST_OFF  73728
#define VB_OFF   81920
#define RV_OFF   40960
#define QH_OFF   114688
#define QL_OFF   118784
#define PF_OFF   114688
#define P2_LDS   147456

__global__ __launch_bounds__(256) void k_pass2(const float* __restrict__ qkv,
                                               const float* __restrict__ relp,
                                               const float* __restrict__ qs,
                                               const float* __restrict__ qh,
                                               const float* __restrict__ simscale,
                                               float* __restrict__ svbuf,
                                               float* __restrict__ svebuf) {
  extern __shared__ char lds[];
  const int it = blockIdx.x, bg = blockIdx.y;
  const int b = bg >> 3, g = bg & 7, i0 = it * 64;
  const int t = threadIdx.x, lane = t & 63, wid = t >> 6;
  const int cg = lane & 15, hi = lane >> 4;
  const float aQK = simscale[g];
  const float aQR = F_QR * simscale[8 + g];
  const float aKR = F_KR * simscale[16 + g];

  // ---- stage Q hi/lo [64 i][32 c] ----
  {
    int c = t >> 3;
    int o = g * 128 + c;
    float sc = qs[o], hh = qh[o];
    const float* src = qkv + ((size_t)b * OO + o) * NN + i0;
#pragma unroll
    for (int r = 0; r < 2; ++r) {
      int i4 = ((t & 7) + 8 * r) * 4;
      float4 v = *(const float4*)(src + i4);
      float vv[4] = {v.x * sc + hh, v.y * sc + hh, v.z * sc + hh, v.w * sc + hh};
#pragma unroll
      for (int e = 0; e < 4; ++e) {
        int iL = i4 + e;
        unsigned short hb = (unsigned short)(__float_as_uint(vv[e]) >> 16);
        unsigned short lb = f2bf_rne(vv[e] - bf2f(hb));
        int off = (iL * 64 + c * 2) ^ ((iL & 3) << 4);
        *(unsigned short*)(lds + QH_OFF + off) = hb;
        *(unsigned short*)(lds + QL_OFF + off) = lb;
      }
    }
  }
  // ---- stage K hi/lo [256 j][32 c] ----
  {
    int c = t & 31;
    int o = g * 128 + 32 + c;
    float sc = qs[o], hh = qh[o];
    const float* src = qkv + ((size_t)b * OO + o) * NN;
    int jg = t >> 5;
#pragma unroll
    for (int r = 0; r < 8; ++r) {
      int j4 = (jg * 8 + r) * 4;
      float4 v = *(const float4*)(src + j4);
      float vv[4] = {v.x * sc + hh, v.y * sc + hh, v.z * sc + hh, v.w * sc + hh};
#pragma unroll
      for (int e = 0; e < 4; ++e) {
        int j = j4 + e;
        unsigned short hb = (unsigned short)(__float_as_uint(vv[e]) >> 16);
        unsigned short lb = f2bf_rne(vv[e] - bf2f(hb));
        int off = (j * 64 + c * 2) ^ ((j & 3) << 4);
        *(unsigned short*)(lds + KH_OFF + off) = hb;
        *(unsigned short*)(lds + KL_OFF + off) = lb;
      }
    }
  }
  // ---- stage Rq [320 u][32 c] transposed: Rq[u][c] = relp[c][i0+u] ----
  {
    int c = t & 31, ug = t >> 5;
    const float* src = relp + c * 512 + i0;
#pragma unroll
    for (int r = 0; r < 10; ++r) {
      int u4 = (ug * 10 + r) * 4;
      float4 v = *(const float4*)(src + u4);
      float vv[4] = {v.x, v.y, v.z, v.w};
#pragma unroll
      for (int e = 0; e < 4; ++e) {
        int u = u4 + e;
        int off = (u * 64 + c * 2) ^ ((u & 3) << 4);
        *(unsigned short*)(lds + RST_OFF + off) = f2bf_rne(vv[e]);
      }
    }
  }
  __syncthreads();

  // ---- qk MFMA (split-3) + M_qr MFMA ----
  f32x4 p[16];
#pragma unroll
  for (int nt = 0; nt < 16; ++nt) p[nt] = (f32x4){0.f, 0.f, 0.f, 0.f};

  int qrow = wid * 16 + cg;
  int qoff = (qrow * 64 + hi * 16) ^ ((qrow & 3) << 4);
  bf16x8 qhf = *(const bf16x8*)(lds + QH_OFF + qoff);
  bf16x8 qlf = *(const bf16x8*)(lds + QL_OFF + qoff);
#pragma unroll
  for (int nt = 0; nt < 16; ++nt) {
    int krow = nt * 16 + cg;
    int kfo = (krow * 64 + hi * 16) ^ ((krow & 3) << 4);
    bf16x8 khf = *(const bf16x8*)(lds + KH_OFF + kfo);
    bf16x8 klf = *(const bf16x8*)(lds + KL_OFF + kfo);
    p[nt] = __builtin_amdgcn_mfma_f32_16x16x32_bf16(qhf, khf, p[nt], 0, 0, 0);
    p[nt] = __builtin_amdgcn_mfma_f32_16x16x32_bf16(qhf, klf, p[nt], 0, 0, 0);
    p[nt] = __builtin_amdgcn_mfma_f32_16x16x32_bf16(qlf, khf, p[nt], 0, 0, 0);
  }
#pragma unroll
  for (int nt = 0; nt < 16; ++nt)
#pragma unroll
    for (int e = 0; e < 4; ++e) p[nt][e] *= aQK;

#pragma unroll
  for (int nt = 0; nt < 20; ++nt) {
    int rrow = nt * 16 + cg;
    int rfo = (rrow * 64 + hi * 16) ^ ((rrow & 3) << 4);
    bf16x8 rf = *(const bf16x8*)(lds + RST_OFF + rfo);
    f32x4 m = (f32x4){0.f, 0.f, 0.f, 0.f};
    m = __builtin_amdgcn_mfma_f32_16x16x32_bf16(qhf, rf, m, 0, 0, 0);
#pragma unroll
    for (int e = 0; e < 4; ++e) {
      int iL = wid * 16 + hi * 4 + e;
      int u = nt * 16 + cg;
      int off = (iL * 640 + u * 2) ^ ((iL & 7) << 4);
      *(unsigned short*)(lds + MG_OFF + off) = f2bf_rne(m[e]);
    }
  }
  __syncthreads();

  // ---- qr gather: p[i,j] += aQR * Mq[iL][iL - j + 255] ----
#pragma unroll
  for (int nt = 0; nt < 16; ++nt)
#pragma unroll
    for (int e = 0; e < 4; ++e) {
      int iL = wid * 16 + hi * 4 + e;
      int ul = iL - (nt * 16 + cg) + 255;
      int off = (iL * 640 + ul * 2) ^ ((iL & 7) << 4);
      p[nt][e] += aQR * bf2f(*(const unsigned short*)(lds + MG_OFF + off));
    }
  // ---- stage Rk [320][32]: Rk[u][c] = relp[32+c][(192-i0)+u] (concurrent w/ gather) ----
  {
    int c = t & 31, ug = t >> 5;
    const float* src = relp + (32 + c) * 512 + (192 - i0);
#pragma unroll
    for (int r = 0; r < 10; ++r) {
      int u4 = (ug * 10 + r) * 4;
      float4 v = *(const float4*)(src + u4);
      float vv[4] = {v.x, v.y, v.z, v.w};
#pragma unroll
      for (int e = 0; e < 4; ++e) {
        int u = u4 + e;
        int off = (u * 64 + c * 2) ^ ((u & 3) << 4);
        *(unsigned short*)(lds + RST_OFF + off) = f2bf_rne(vv[e]);
      }
    }
  }
  __syncthreads();

  // ---- G MFMA: G[j][sl] = sum_c k[c,j]*relp[32+c][jt*16+192-i0+sl] ----
#pragma unroll
  for (int jj = 0; jj < 4; ++jj) {
    int jt = wid * 4 + jj;
    int arow = jt * 16 + cg;
    int afo = (arow * 64 + hi * 16) ^ ((arow & 3) << 4);
    bf16x8 kf = *(const bf16x8*)(lds + KH_OFF + afo);
#pragma unroll
    for (int n5 = 0; n5 < 5; ++n5) {
      int brow = jt * 16 + n5 * 16 + cg;
      int bfo = (brow * 64 + hi * 16) ^ ((brow & 3) << 4);
      bf16x8 rf = *(const bf16x8*)(lds + RST_OFF + bfo);
      f32x4 gacc = (f32x4){0.f, 0.f, 0.f, 0.f};
      gacc = __builtin_amdgcn_mfma_f32_16x16x32_bf16(kf, rf, gacc, 0, 0, 0);
#pragma unroll
      for (int e = 0; e < 4; ++e) {
        int j = jt * 16 + hi * 4 + e;
        int sl = n5 * 16 + cg;
        int off = (j * 160 + sl * 2) ^ ((j & 7) << 4);
        *(unsigned short*)(lds + MG_OFF + off) = f2bf_rne(gacc[e]);
      }
    }
  }
  __syncthreads();

  // ---- kr gather: p[i,j] += aKR * G[j][cg + 63 - iL] ----
#pragma unroll
  for (int nt = 0; nt < 16; ++nt)
#pragma unroll
    for (int e = 0; e < 4; ++e) {
      int iL = wid * 16 + hi * 4 + e;
      int j = nt * 16 + cg;
      int sl = cg + 63 - iL;
      int off = (j * 160 + sl * 2) ^ ((j & 7) << 4);
      p[nt][e] += aKR * bf2f(*(const unsigned short*)(lds + MG_OFF + off));
    }

  // ---- softmax over j (16 nt regs x 16 cg lanes); BN shift is softmax-invariant ----
#pragma unroll
  for (int e = 0; e < 4; ++e) {
    float m = p[0][e];
#pragma unroll
    for (int nt = 1; nt < 16; ++nt) m = fmaxf(m, p[nt][e]);
#pragma unroll
    for (int k = 1; k < 16; k <<= 1) m = fmaxf(m, __shfl_xor(m, k));
    float s = 0.f;
#pragma unroll
    for (int nt = 0; nt < 16; ++nt) { float ev = __expf(p[nt][e] - m); p[nt][e] = ev; s += ev; }
#pragma unroll
    for (int k = 1; k < 16; k <<= 1) s += __shfl_xor(s, k);
    float inv = 1.f / s;
#pragma unroll
    for (int nt = 0; nt < 16; ++nt) p[nt][e] *= inv;
  }
  __syncthreads();

  // ---- zero Ps (40KB) ----
  {
    float4 z = {0.f, 0.f, 0.f, 0.f};
#pragma unroll
    for (int r = 0; r < 10; ++r) *(float4*)(lds + MG_OFF + t * 16 + r * 4096) = z;
  }
  __syncthreads();

  // ---- write Pf & Ps (bf16, swizzled); stage Vb, Rv ----
#pragma unroll
  for (int nt = 0; nt < 16; ++nt)
#pragma unroll
    for (int e = 0; e < 4; ++e) {
      int iL = wid * 16 + hi * 4 + e;
      int j = nt * 16 + cg;
      unsigned short hv = f2bf_rne(p[nt][e]);
      *(unsigned short*)(lds + PF_OFF + ((iL * 512 + j * 2) ^ ((iL & 7) << 4))) = hv;
      int us = iL + 255 - j;
      *(unsigned short*)(lds + MG_OFF + ((iL * 640 + us * 2) ^ ((iL & 7) << 4))) = hv;
    }
  {
#pragma unroll
    for (int r = 0; r < 16; ++r) {
      int id = r * 256 + t;
      int cp = id & 63, ch = id >> 6;
      int o = g * 128 + 64 + cp;
      float sc = qs[o], hh = qh[o];
      float4 v = *(const float4*)(qkv + ((size_t)b * OO + o) * NN + ch * 4);
      short4 s4 = make_short4(f2bf_rne(v.x * sc + hh), f2bf_rne(v.y * sc + hh),
                              f2bf_rne(v.z * sc + hh), f2bf_rne(v.w * sc + hh));
      *(short4*)(lds + VB_OFF + ((cp * 512 + ch * 8) ^ ((cp & 7) << 4))) = s4;
    }
#pragma unroll
    for (int r = 0; r < 20; ++r) {
      int id = r * 256 + t;
      int cp = id & 63, ch = id >> 6;
      float4 v = *(const float4*)(relp + (size_t)(64 + cp) * 512 + i0 + ch * 4);
      short4 s4 = make_short4(f2bf_rne(v.x), f2bf_rne(v.y), f2bf_rne(v.z), f2bf_rne(v.w));
      *(short4*)(lds + RV_OFF + ((cp * 640 + ch * 8) ^ ((cp & 7) << 4))) = s4;
    }
  }
  __syncthreads();

  // ---- sv = p . v^T  and  sve = Ps . Rv^T  via MFMA ----
  {
    int prow = wid * 16 + cg;
    bf16x8 af[8];
#pragma unroll
    for (int ks = 0; ks < 8; ++ks)
      af[ks] = *(const bf16x8*)(lds + PF_OFF + ((prow * 512 + ks * 64 + hi * 16) ^ ((prow & 7) << 4)));
#pragma unroll
    for (int nt = 0; nt < 4; ++nt) {
      int vrow = nt * 16 + cg;
      f32x4 acc = (f32x4){0.f, 0.f, 0.f, 0.f};
#pragma unroll
      for (int ks = 0; ks < 8; ++ks) {
        bf16x8 bfv = *(const bf16x8*)(lds + VB_OFF + ((vrow * 512 + ks * 64 + hi * 16) ^ ((vrow & 7) << 4)));
        acc = __builtin_amdgcn_mfma_f32_16x16x32_bf16(af[ks], bfv, acc, 0, 0, 0);
      }
      int cp = g * 64 + nt * 16 + cg;
      float* dst = svbuf + ((size_t)(b * 512 + cp)) * NN + i0 + wid * 16 + hi * 4;
      *(float4*)dst = make_float4(acc[0], acc[1], acc[2], acc[3]);
    }
    bf16x8 ae[10];
#pragma unroll
    for (int ks = 0; ks < 10; ++ks)
      ae[ks] = *(const bf16x8*)(lds + MG_OFF + ((prow * 640 + ks * 64 + hi * 16) ^ ((prow & 7) << 4)));
#pragma unroll
    for (int nt = 0; nt < 4; ++nt) {
      int rrow = nt * 16 + cg;
      f32x4 acc = (f32x4){0.f, 0.f, 0.f, 0.f};
#pragma unroll
      for (int ks = 0; ks < 10; ++ks) {
        bf16x8 bfr = *(const bf16x8*)(lds + RV_OFF + ((rrow * 640 + ks * 64 + hi * 16) ^ ((rrow & 7) << 4)));
        acc = __builtin_amdgcn_mfma_f32_16x16x32_bf16(ae[ks], bfr, acc, 0, 0, 0);
      }
      int cp = g * 64 + nt * 16 + cg;
      float* dst = svebuf + ((size_t)(b * 512 + cp)) * NN + i0 + wid * 16 + hi * 4;
      *(float4*)dst = make_float4(acc[0] * F_SVE, acc[1] * F_SVE, acc[2] * F_SVE, acc[3] * F_SVE);
    }
  }
}

// ---------------- K6: final BN stats over sv / sve ----------------
__global__ __launch_bounds__(256) void k_out_stats(const float* __restrict__ svbuf,
                                                   const float* __restrict__ svebuf,
                                                   const float* __restrict__ go,
                                                   const float* __restrict__ bo,
                                                   float* __restrict__ osc,
                                                   float* __restrict__ osh) {
  const int bid = blockIdx.x;
  const int arr = bid >> 9, pch = bid & 511;
  const float* buf = arr ? svebuf : svbuf;
  const int t = threadIdx.x;
  float s = 0.f, ss = 0.f;
  for (int b = 0; b < BB; ++b) {
    float v = buf[((size_t)b * 512 + pch) * NN + t];
    s += v; ss += v * v;
  }
#pragma unroll
  for (int m = 1; m < 64; m <<= 1) { s += __shfl_xor(s, m); ss += __shfl_xor(ss, m); }
  __shared__ float rs[4], rss[4];
  int wv = t >> 6;
  if ((t & 63) == 0) { rs[wv] = s; rss[wv] = ss; }
  __syncthreads();
  if (t == 0) {
    s = rs[0] + rs[1] + rs[2] + rs[3];
    ss = rss[0] + rss[1] + rss[2] + rss[3];
    const float inv = 1.f / 16384.f;
    float m = s * inv;
    float var = ss * inv - m * m;
    float r = rsqrtf(var + 1e-5f);
    int o = pch * 2 + arr;
    float sc = go[o] * r;
    osc[bid] = sc;
    osh[bid] = bo[o] - m * sc;
  }
}

// ---------------- K7: combine ----------------
__global__ __launch_bounds__(256) void k_final(const float* __restrict__ svbuf,
                                               const float* __restrict__ svebuf,
                                               const float* __restrict__ osc,
                                               const float* __restrict__ osh,
                                               float* __restrict__ out) {
  const size_t f = (size_t)blockIdx.x * 256 + threadIdx.x;
  const int pch = (int)((f >> 6) & 511);
  float4 a = ((const float4*)svbuf)[f];
  float4 e = ((const float4*)svebuf)[f];
  float s1 = osc[pch], h1 = osh[pch];
  float s2 = osc[512 + pch], h2 = osh[512 + pch];
  float hh = h1 + h2;
  float4 o;
  o.x = a.x * s1 + e.x * s2 + hh;
  o.y = a.y * s1 + e.y * s2 + hh;
  o.z = a.z * s1 + e.z * s2 + hh;
  o.w = a.w * s1 + e.w * s2 + hh;
  ((float4*)out)[f] = o;
}

extern "C" void kernel_launch(void* const* d_in, const int* in_sizes, int n_in,
                              void* d_out, int out_size, void* d_ws, size_t ws_size,
                              hipStream_t stream) {
  const float* x     = (const float*)d_in[0];
  const float* w     = (const float*)d_in[1];
  const float* rel   = (const float*)d_in[2];
  const float* g_qkv = (const float*)d_in[3];
  const float* b_qkv = (const float*)d_in[4];
  const float* g_sim = (const float*)d_in[5];
  const float* b_sim = (const float*)d_in[6];
  const float* g_out = (const float*)d_in[7];
  const float* b_out = (const float*)d_in[8];

  float* ws = (float*)d_ws;
  float* qkv      = ws;
  float* sv       = qkv + 16777216;
  float* sve      = sv + 8388608;
  float* qs       = sve + 8388608;
  float* qh       = qs + 1024;
  float* simacc   = qh + 1024;
  float* simscale = simacc + 48;
  float* simshift = simscale + 24;
  float* osc      = simshift + 8;
  float* osh      = osc + 1024;

  float* relp = (float*)d_out;

  float* Wbuf = sv;
  float* Rbuf = sv + 524288;

  hipFuncSetAttribute((const void*)k_pass2, hipFuncAttributeMaxDynamicSharedMemorySize, P2_LDS);

  hipMemsetAsync(simacc, 0, 48 * sizeof(float), stream);

  k_relpad<<<128, 256, 0, stream>>>(rel, relp);
  k_wprep<<<32, 256, 0, stream>>>(relp, Wbuf, Rbuf);
  k_qkv_gemm<<<dim3(2, 8, 64), 256, 0, stream>>>(x, w, qkv);
  k_qkv_stats<<<1024, 256, 0, stream>>>(qkv, g_qkv, b_qkv, qs, qh);
  k_simstats<<<512, 256, 0, stream>>>(qkv, Wbuf, Rbuf, qs, qh, simacc);
  k_sim_finalize<<<1, 32, 0, stream>>>(simacc, g_sim, b_sim, simscale, simshift);
  k_pass2<<<dim3(4, 512), 256, P2_LDS, stream>>>(qkv, relp, qs, qh, simscale, sv, sve);
  k_out_stats<<<1024, 256, 0, stream>>>(sv, sve, g_out, b_out, osc, osh);
  k_final<<<8192, 256, 0, stream>>>(sv, sve, osc, osh, (float*)d_out);
}

// Round 7
// 528.513 us; speedup vs baseline: 2.9281x; 1.1605x over previous
//
#include <hip/hip_runtime.h>

#define NN 256
#define CC 512
#define OO 1024
#define BB 64

#define F_QR 0.1f
#define F_KR 0.1f
#define F_SVE 0.1f

typedef __attribute__((ext_vector_type(8))) short bf16x8;
typedef __attribute__((ext_vector_type(4))) float f32x4;

__device__ inline unsigned short f2bf_rne(float f) {
  unsigned u = __float_as_uint(f);
  u += 0x7fffu + ((u >> 16) & 1u);
  return (unsigned short)(u >> 16);
}

__device__ inline float bf2f(unsigned short h) {
  return __uint_as_float((unsigned)h << 16);
}

// ---------------- K0: pad rel rows 511 -> 512 ----------------
__global__ void k_relpad(const float* __restrict__ rel, float* __restrict__ relp) {
  const int row = blockIdx.x;
  const int t = threadIdx.x;
  for (int u = t; u < 511; u += 256) relp[row * 512 + u] = rel[row * 511 + u];
  if (t == 0) relp[row * 512 + 511] = 0.f;
}

// ---------------- K1: qkv GEMM (split-bf16 MFMA, verified round 5) ----------------
__global__ __launch_bounds__(256) void k_qkv_gemm(const float* __restrict__ x,
                                                  const float* __restrict__ w,
                                                  float* __restrict__ qkv) {
  __shared__ unsigned short Ah[128][40];
  __shared__ unsigned short Al[128][40];
  __shared__ unsigned short Bh[128][40];
  __shared__ unsigned short Bl[128][40];

  const int b = blockIdx.z, o0 = blockIdx.y * 128, n0 = blockIdx.x * 128;
  const int t = threadIdx.x;
  const int lane = t & 63, wid = t >> 6;
  const int wr = wid >> 1, wc = wid & 1;
  const int frow = lane & 15;
  const int koff = (lane >> 4) * 8;

  f32x4 acc[4][4];
#pragma unroll
  for (int i = 0; i < 4; ++i)
#pragma unroll
    for (int j = 0; j < 4; ++j) acc[i][j] = (f32x4){0.f, 0.f, 0.f, 0.f};

  const float* wb = w + (size_t)o0 * CC;
  const float* xb = x + (size_t)b * NN * CC + (size_t)n0 * CC;

  for (int c0 = 0; c0 < CC; c0 += 32) {
    if (c0) __syncthreads();
#pragma unroll
    for (int r = 0; r < 4; ++r) {
      int idx = t + 256 * r;
      int row = idx >> 3, c4 = idx & 7;
      float4 va = *(const float4*)(wb + (size_t)row * CC + c0 + c4 * 4);
      float4 vb = *(const float4*)(xb + (size_t)row * CC + c0 + c4 * 4);
      float af[4] = {va.x, va.y, va.z, va.w};
      float bf[4] = {vb.x, vb.y, vb.z, vb.w};
      unsigned short ah4[4], al4[4], bh4[4], bl4[4];
#pragma unroll
      for (int e = 0; e < 4; ++e) {
        unsigned ua = __float_as_uint(af[e]);
        unsigned short ha = (unsigned short)(ua >> 16);
        ah4[e] = ha;
        al4[e] = f2bf_rne(af[e] - bf2f(ha));
        unsigned ub = __float_as_uint(bf[e]);
        unsigned short hb = (unsigned short)(ub >> 16);
        bh4[e] = hb;
        bl4[e] = f2bf_rne(bf[e] - bf2f(hb));
      }
      *(short4*)&Ah[row][c4 * 4] = make_short4(ah4[0], ah4[1], ah4[2], ah4[3]);
      *(short4*)&Al[row][c4 * 4] = make_short4(al4[0], al4[1], al4[2], al4[3]);
      *(short4*)&Bh[row][c4 * 4] = make_short4(bh4[0], bh4[1], bh4[2], bh4[3]);
      *(short4*)&Bl[row][c4 * 4] = make_short4(bl4[0], bl4[1], bl4[2], bl4[3]);
    }
    __syncthreads();

    bf16x8 fah[4], fal[4], fbh[4], fbl[4];
#pragma unroll
    for (int mi = 0; mi < 4; ++mi) {
      int rr = wr * 64 + mi * 16 + frow;
      fah[mi] = *(const bf16x8*)&Ah[rr][koff];
      fal[mi] = *(const bf16x8*)&Al[rr][koff];
    }
#pragma unroll
    for (int nj = 0; nj < 4; ++nj) {
      int rr = wc * 64 + nj * 16 + frow;
      fbh[nj] = *(const bf16x8*)&Bh[rr][koff];
      fbl[nj] = *(const bf16x8*)&Bl[rr][koff];
    }
#pragma unroll
    for (int mi = 0; mi < 4; ++mi)
#pragma unroll
      for (int nj = 0; nj < 4; ++nj) {
        acc[mi][nj] = __builtin_amdgcn_mfma_f32_16x16x32_bf16(fah[mi], fbh[nj], acc[mi][nj], 0, 0, 0);
        acc[mi][nj] = __builtin_amdgcn_mfma_f32_16x16x32_bf16(fah[mi], fbl[nj], acc[mi][nj], 0, 0, 0);
        acc[mi][nj] = __builtin_amdgcn_mfma_f32_16x16x32_bf16(fal[mi], fbh[nj], acc[mi][nj], 0, 0, 0);
      }
  }

#pragma unroll
  for (int mi = 0; mi < 4; ++mi) {
    int orow = o0 + wr * 64 + mi * 16 + (lane >> 4) * 4;
#pragma unroll
    for (int nj = 0; nj < 4; ++nj) {
      int ncol = n0 + wc * 64 + nj * 16 + frow;
      float* dst = qkv + ((size_t)b * OO + orow) * NN + ncol;
#pragma unroll
      for (int j = 0; j < 4; ++j) dst[(size_t)j * NN] = acc[mi][nj][j];
    }
  }
}

// ---------------- K2: per-channel BN scale/shift for qkv ----------------
__global__ __launch_bounds__(256) void k_qkv_stats(const float* __restrict__ qkv,
                                                   const float* __restrict__ gq,
                                                   const float* __restrict__ bq,
                                                   float* __restrict__ qs,
                                                   float* __restrict__ qh) {
  const int o = blockIdx.x;
  const int t = threadIdx.x;
  float s = 0.f, ss = 0.f;
  for (int b = 0; b < BB; ++b) {
    float v = qkv[((size_t)b * OO + o) * NN + t];
    s += v; ss += v * v;
  }
#pragma unroll
  for (int m = 1; m < 64; m <<= 1) { s += __shfl_xor(s, m); ss += __shfl_xor(ss, m); }
  __shared__ float rs[4], rss[4];
  int wv = t >> 6;
  if ((t & 63) == 0) { rs[wv] = s; rss[wv] = ss; }
  __syncthreads();
  if (t == 0) {
    s = rs[0] + rs[1] + rs[2] + rs[3];
    ss = rss[0] + rss[1] + rss[2] + rss[3];
    const float inv = 1.f / (float)(BB * NN);
    float m = s * inv;
    float var = ss * inv - m * m;
    float r = rsqrtf(var + 1e-5f);
    float sc = gq[o] * r;
    qs[o] = sc;
    qh[o] = bq[o] - m * sc;
  }
}

// ---------------- K3a: sliding-window correlation tables for rel ----------------
__global__ __launch_bounds__(256) void k_wprep(const float* __restrict__ relp,
                                               float* __restrict__ W,
                                               float* __restrict__ R) {
  const int gid = blockIdx.x * 256 + threadIdx.x;
  const int pid = gid >> 2;
  const int i0 = (gid & 3) * 64;
  const int term = pid >> 10, c = (pid >> 5) & 31, cp = pid & 31;
  const float* ra = relp + (term * 32 + c) * 512;
  const float* rb = relp + (term * 32 + cp) * 512;
  float w = 0.f;
  for (int u = i0; u < i0 + 256; ++u) w += ra[u] * rb[u];
  float* Wp = W + pid * 256;
  Wp[i0] = w;
  for (int i = i0 + 1; i < i0 + 64; ++i) {
    w += ra[i + 255] * rb[i + 255] - ra[i - 1] * rb[i - 1];
    Wp[i] = w;
  }
  if (cp == 0) {
    float s = 0.f;
    for (int u = i0; u < i0 + 256; ++u) s += ra[u];
    float* Rp = R + (term * 32 + c) * 256;
    Rp[i0] = s;
    for (int i = i0 + 1; i < i0 + 64; ++i) { s += ra[i + 255] - ra[i - 1]; Rp[i] = s; }
  }
}

// ---------------- K3b: algebraic BN stats for qk/qr/kr ----------------
__global__ __launch_bounds__(256) void k_simstats(const float* __restrict__ qkv,
                                                  const float* __restrict__ Wbuf,
                                                  const float* __restrict__ Rbuf,
                                                  const float* __restrict__ qs,
                                                  const float* __restrict__ qh,
                                                  float* __restrict__ simacc) {
  __shared__ float sh[64 * 260];
  __shared__ float qsum[4][32], ksum[4][32];
  const int b = blockIdx.x >> 3, g = blockIdx.x & 7;
  const int t = threadIdx.x;
  const int wv = t >> 6, ln = t & 63;

#pragma unroll 1
  for (int c = 0; c < 32; ++c) {
    int oq = g * 128 + c;
    int ok = g * 128 + 32 + c;
    sh[c * 260 + t] = qkv[((size_t)b * OO + oq) * NN + t] * qs[oq] + qh[oq];
    sh[(32 + c) * 260 + t] = qkv[((size_t)b * OO + ok) * NN + t] * qs[ok] + qh[ok];
  }
  __syncthreads();

  float ss_qr = 0.f, ss_kr = 0.f, s_qr = 0.f, s_kr = 0.f;
  const float* Wq = Wbuf + t;
  const float* Wk = Wbuf + 1024 * 256 + t;
  const float* Rq = Rbuf + t;
#pragma unroll 1
  for (int c = 0; c < 32; ++c) {
    float qc = sh[c * 260 + t];
    float kc = sh[(32 + c) * 260 + t];
    s_qr += qc * Rq[c * 256];
    s_kr += kc * Rq[(32 + c) * 256];
    ss_qr += qc * qc * Wq[(c * 33) * 256];
    ss_kr += kc * kc * Wk[(c * 33) * 256];
    float qc2 = qc + qc, kc2 = kc + kc;
#pragma unroll 4
    for (int cp = c + 1; cp < 32; ++cp) {
      ss_qr += qc2 * sh[cp * 260 + t] * Wq[(c * 32 + cp) * 256];
      ss_kr += kc2 * sh[(32 + cp) * 260 + t] * Wk[(c * 32 + cp) * 256];
    }
  }

  float ss_qk = 0.f;
#pragma unroll 1
  for (int pp = 0; pp < 4; ++pp) {
    int p = t + 256 * pp;
    int c = p >> 5, cp = p & 31;
    const float* qa = &sh[c * 260];
    const float* qb = &sh[cp * 260];
    const float* ka = &sh[(32 + c) * 260];
    const float* kb = &sh[(32 + cp) * 260];
    float gq = 0.f, gk = 0.f;
#pragma unroll 4
    for (int i = 0; i < 256; i += 4) {
      float4 a = *(const float4*)&qa[i];
      float4 bq = *(const float4*)&qb[i];
      gq += a.x * bq.x + a.y * bq.y + a.z * bq.z + a.w * bq.w;
      float4 ak = *(const float4*)&ka[i];
      float4 bk = *(const float4*)&kb[i];
      gk += ak.x * bk.x + ak.y * bk.y + ak.z * bk.z + ak.w * bk.w;
    }
    ss_qk += gq * gk;
  }

#pragma unroll
  for (int m = 1; m < 64; m <<= 1) {
    ss_qk += __shfl_xor(ss_qk, m);
    ss_qr += __shfl_xor(ss_qr, m);
    ss_kr += __shfl_xor(ss_kr, m);
    s_qr += __shfl_xor(s_qr, m);
    s_kr += __shfl_xor(s_kr, m);
  }
  if (ln == 0) {
    atomicAdd(&simacc[24 + g], ss_qk);
    atomicAdd(&simacc[24 + 8 + g], ss_qr * (F_QR * F_QR));
    atomicAdd(&simacc[24 + 16 + g], ss_kr * (F_KR * F_KR));
    atomicAdd(&simacc[8 + g], s_qr * F_QR);
    atomicAdd(&simacc[16 + g], s_kr * F_KR);
  }

#pragma unroll 1
  for (int c = 0; c < 32; ++c) {
    float a = sh[c * 260 + t], bb2 = sh[(32 + c) * 260 + t];
#pragma unroll
    for (int m = 1; m < 64; m <<= 1) { a += __shfl_xor(a, m); bb2 += __shfl_xor(bb2, m); }
    if (ln == 0) { qsum[wv][c] = a; ksum[wv][c] = bb2; }
  }
  __syncthreads();
  if (t < 32) {
    float a = qsum[0][t] + qsum[1][t] + qsum[2][t] + qsum[3][t];
    float bb2 = ksum[0][t] + ksum[1][t] + ksum[2][t] + ksum[3][t];
    qsum[0][t] = a * bb2;
  }
  __syncthreads();
  if (t == 0) {
    float s = 0.f;
#pragma unroll
    for (int c = 0; c < 32; ++c) s += qsum[0][c];
    atomicAdd(&simacc[g], s);
  }
}

// ---------------- finalize sim BN coefficients ----------------
__global__ void k_sim_finalize(const float* __restrict__ simacc,
                               const float* __restrict__ gs,
                               const float* __restrict__ bs,
                               float* __restrict__ simscale,
                               float* __restrict__ simshift) {
  const int t = threadIdx.x;
  __shared__ float sh[24];
  if (t < 24) {
    const float inv = 1.f / (64.f * 256.f * 256.f);
    float m = simacc[t] * inv;
    float var = simacc[24 + t] * inv - m * m;
    float a = gs[t] * rsqrtf(var + 1e-5f);
    simscale[t] = a;
    sh[t] = bs[t] - m * a;
  }
  __syncthreads();
  if (t < 8) simshift[t] = sh[t] + sh[8 + t] + sh[16 + t];
}

// ---------------- pass2: all-MFMA, 8 waves, pitched LDS (no XOR swizzle) -------
// Pitches: QP=80B rows for Q/K/RST (32 chans); MQP=656B (Mq/Ps, 320+8 shorts);
// GP=176B (G, 80+8 shorts); PFP=528B (PF/VB, 256+8 shorts); RVP=656B (RV).
// Layout (bytes): MG [0,45056) Mq/G/Ps + smx/sms; KH [45056,65536);
// KL [65536,86016); RST [86016,111616); QH [111616,116736); QL [116736,121856).
// Phase B aliases: VB [45056,78848); PF [86016,119808); RV [121856,163840).
#define MG_OFF   0
#define SMX_OFF  0
#define SMS_OFF  512
#define KH_OFF   45056
#define KL_OFF   65536
#define RST_OFF  86016
#define QH_OFF   111616
#define QL_OFF   116736
#define VB_OFF   45056
#define PF_OFF   86016
#define RV_OFF   121856
#define P2_LDS   163840
#define QP  80
#define MQP 656
#define GP  176
#define PFP 528
#define RVP 656

__global__ __launch_bounds__(512) void k_pass2(const float* __restrict__ qkv,
                                               const float* __restrict__ relp,
                                               const float* __restrict__ qs,
                                               const float* __restrict__ qh,
                                               const float* __restrict__ simscale,
                                               float* __restrict__ svbuf,
                                               float* __restrict__ svebuf) {
  extern __shared__ char lds[];
  const int it = blockIdx.x, bg = blockIdx.y;
  const int b = bg >> 3, g = bg & 7, i0 = it * 64;
  const int t = threadIdx.x, lane = t & 63, wid = t >> 6;
  const int cg = lane & 15, hi = lane >> 4;
  const int wi = wid & 3, wj = wid >> 2;   // i-tile, j-half
  const float aQK = simscale[g];
  const float aQR = F_QR * simscale[8 + g];
  const float aKR = F_KR * simscale[16 + g];

  // ---- stage Q [64 i][32 c] hi/lo ----
  {
    int c = t >> 4;
    int o = g * 128 + c;
    float sc = qs[o], hh = qh[o];
    int i4 = (t & 15) * 4;
    float4 v = *(const float4*)(qkv + ((size_t)b * OO + o) * NN + i0 + i4);
    float vv[4] = {v.x * sc + hh, v.y * sc + hh, v.z * sc + hh, v.w * sc + hh};
#pragma unroll
    for (int e = 0; e < 4; ++e) {
      int iL = i4 + e;
      unsigned short hb = (unsigned short)(__float_as_uint(vv[e]) >> 16);
      *(unsigned short*)(lds + QH_OFF + iL * QP + c * 2) = hb;
      *(unsigned short*)(lds + QL_OFF + iL * QP + c * 2) = f2bf_rne(vv[e] - bf2f(hb));
    }
  }
  // ---- stage K [256 j][32 c] hi/lo ----
  {
    int c = t >> 4;
    int o = g * 128 + 32 + c;
    float sc = qs[o], hh = qh[o];
    const float* src = qkv + ((size_t)b * OO + o) * NN;
#pragma unroll
    for (int r = 0; r < 4; ++r) {
      int j4 = ((t & 15) + 16 * r) * 4;
      float4 v = *(const float4*)(src + j4);
      float vv[4] = {v.x * sc + hh, v.y * sc + hh, v.z * sc + hh, v.w * sc + hh};
#pragma unroll
      for (int e = 0; e < 4; ++e) {
        int j = j4 + e;
        unsigned short hb = (unsigned short)(__float_as_uint(vv[e]) >> 16);
        *(unsigned short*)(lds + KH_OFF + j * QP + c * 2) = hb;
        *(unsigned short*)(lds + KL_OFF + j * QP + c * 2) = f2bf_rne(vv[e] - bf2f(hb));
      }
    }
  }
  // ---- stage Rq [320 u][32 c]: Rq[u][c] = relp[c][i0+u] ----
  {
    int c = t >> 4;
    const float* src = relp + c * 512 + i0;
#pragma unroll
    for (int r = 0; r < 5; ++r) {
      int u4 = ((t & 15) + 16 * r) * 4;
      float4 v = *(const float4*)(src + u4);
      float vv[4] = {v.x, v.y, v.z, v.w};
#pragma unroll
      for (int e = 0; e < 4; ++e)
        *(unsigned short*)(lds + RST_OFF + (u4 + e) * QP + c * 2) = f2bf_rne(vv[e]);
    }
  }
  __syncthreads();

  // ---- qk MFMA (split-3): each wave owns (i-tile wi) x (j-half wj) ----
  f32x4 p[8];
#pragma unroll
  for (int n = 0; n < 8; ++n) p[n] = (f32x4){0.f, 0.f, 0.f, 0.f};

  int qrow = wi * 16 + cg;
  bf16x8 qhf = *(const bf16x8*)(lds + QH_OFF + qrow * QP + hi * 16);
  bf16x8 qlf = *(const bf16x8*)(lds + QL_OFF + qrow * QP + hi * 16);
#pragma unroll
  for (int n = 0; n < 8; ++n) {
    int krow = (wj * 8 + n) * 16 + cg;
    bf16x8 khf = *(const bf16x8*)(lds + KH_OFF + krow * QP + hi * 16);
    bf16x8 klf = *(const bf16x8*)(lds + KL_OFF + krow * QP + hi * 16);
    p[n] = __builtin_amdgcn_mfma_f32_16x16x32_bf16(qhf, khf, p[n], 0, 0, 0);
    p[n] = __builtin_amdgcn_mfma_f32_16x16x32_bf16(qhf, klf, p[n], 0, 0, 0);
    p[n] = __builtin_amdgcn_mfma_f32_16x16x32_bf16(qlf, khf, p[n], 0, 0, 0);
  }
#pragma unroll
  for (int n = 0; n < 8; ++n)
#pragma unroll
    for (int e = 0; e < 4; ++e) p[n][e] *= aQK;

  // ---- Mq MFMA: Mq[iL][u] = sum_c q[c,i]*Rq[u][c]; u-tiles split by wj ----
#pragma unroll
  for (int m5 = 0; m5 < 10; ++m5) {
    int ntq = wj * 10 + m5;
    bf16x8 rf = *(const bf16x8*)(lds + RST_OFF + (ntq * 16 + cg) * QP + hi * 16);
    f32x4 m = (f32x4){0.f, 0.f, 0.f, 0.f};
    m = __builtin_amdgcn_mfma_f32_16x16x32_bf16(qhf, rf, m, 0, 0, 0);
#pragma unroll
    for (int e = 0; e < 4; ++e) {
      int iL = wi * 16 + hi * 4 + e;
      *(unsigned short*)(lds + MG_OFF + iL * MQP + (ntq * 16 + cg) * 2) = f2bf_rne(m[e]);
    }
  }
  __syncthreads();

  // ---- qr gather + Rk re-stage ----
#pragma unroll
  for (int n = 0; n < 8; ++n)
#pragma unroll
    for (int e = 0; e < 4; ++e) {
      int iL = wi * 16 + hi * 4 + e;
      int ul = iL - ((wj * 8 + n) * 16 + cg) + 255;
      p[n][e] += aQR * bf2f(*(const unsigned short*)(lds + MG_OFF + iL * MQP + ul * 2));
    }
  {
    int c = t >> 4;
    const float* src = relp + (32 + c) * 512 + (192 - i0);
#pragma unroll
    for (int r = 0; r < 5; ++r) {
      int u4 = ((t & 15) + 16 * r) * 4;
      float4 v = *(const float4*)(src + u4);
      float vv[4] = {v.x, v.y, v.z, v.w};
#pragma unroll
      for (int e = 0; e < 4; ++e)
        *(unsigned short*)(lds + RST_OFF + (u4 + e) * QP + c * 2) = f2bf_rne(vv[e]);
    }
  }
  __syncthreads();

  // ---- G MFMA: G[j][sl] = sum_c k[c,j]*Rk[jt*16+sl][c]; 2 j-tiles per wave ----
#pragma unroll
  for (int jj = 0; jj < 2; ++jj) {
    int jt = wid * 2 + jj;
    bf16x8 kf = *(const bf16x8*)(lds + KH_OFF + (jt * 16 + cg) * QP + hi * 16);
#pragma unroll
    for (int n5 = 0; n5 < 5; ++n5) {
      bf16x8 rf = *(const bf16x8*)(lds + RST_OFF + ((jt + n5) * 16 + cg) * QP + hi * 16);
      f32x4 gacc = (f32x4){0.f, 0.f, 0.f, 0.f};
      gacc = __builtin_amdgcn_mfma_f32_16x16x32_bf16(kf, rf, gacc, 0, 0, 0);
#pragma unroll
      for (int e = 0; e < 4; ++e) {
        int j = jt * 16 + hi * 4 + e;
        *(unsigned short*)(lds + MG_OFF + j * GP + (n5 * 16 + cg) * 2) = f2bf_rne(gacc[e]);
      }
    }
  }
  __syncthreads();

  // ---- kr gather: p[i,j] += aKR * G[j][cg + 63 - iL] ----
#pragma unroll
  for (int n = 0; n < 8; ++n)
#pragma unroll
    for (int e = 0; e < 4; ++e) {
      int iL = wi * 16 + hi * 4 + e;
      int j = (wj * 8 + n) * 16 + cg;
      int sl = cg + 63 - iL;
      p[n][e] += aKR * bf2f(*(const unsigned short*)(lds + MG_OFF + j * GP + sl * 2));
    }
  __syncthreads();  // G reads done before smx writes below

  // ---- softmax over j, cross-wave (wj halves) ----
  {
    float mloc[4];
#pragma unroll
    for (int e = 0; e < 4; ++e) {
      float m = p[0][e];
#pragma unroll
      for (int n = 1; n < 8; ++n) m = fmaxf(m, p[n][e]);
#pragma unroll
      for (int k = 1; k < 16; k <<= 1) m = fmaxf(m, __shfl_xor(m, k));
      mloc[e] = m;
    }
    if (cg == 0) {
#pragma unroll
      for (int e = 0; e < 4; ++e)
        *(float*)(lds + SMX_OFF + (wj * 64 + wi * 16 + hi * 4 + e) * 4) = mloc[e];
    }
    __syncthreads();
    float sloc[4];
#pragma unroll
    for (int e = 0; e < 4; ++e) {
      int iL = wi * 16 + hi * 4 + e;
      float m = fmaxf(*(const float*)(lds + SMX_OFF + iL * 4),
                      *(const float*)(lds + SMX_OFF + (64 + iL) * 4));
      float s = 0.f;
#pragma unroll
      for (int n = 0; n < 8; ++n) { float ev = __expf(p[n][e] - m); p[n][e] = ev; s += ev; }
#pragma unroll
      for (int k = 1; k < 16; k <<= 1) s += __shfl_xor(s, k);
      sloc[e] = s;
    }
    if (cg == 0) {
#pragma unroll
      for (int e = 0; e < 4; ++e)
        *(float*)(lds + SMS_OFF + (wj * 64 + wi * 16 + hi * 4 + e) * 4) = sloc[e];
    }
    __syncthreads();
#pragma unroll
    for (int e = 0; e < 4; ++e) {
      int iL = wi * 16 + hi * 4 + e;
      float s = *(const float*)(lds + SMS_OFF + iL * 4) +
                *(const float*)(lds + SMS_OFF + (64 + iL) * 4);
      float inv = 1.f / s;
#pragma unroll
      for (int n = 0; n < 8; ++n) p[n][e] *= inv;
    }
  }
  __syncthreads();  // sms reads done before zeroing MG

  // ---- zero MG region (Ps needs zero outside the skew band) ----
#pragma unroll
  for (int r = 0; r < 6; ++r) {
    int idx = r * 512 + t;
    if (idx < 2816) *(float4*)(lds + idx * 16) = make_float4(0.f, 0.f, 0.f, 0.f);
  }
  __syncthreads();

  // ---- write PF + skewed Ps (bf16); stage VB + RV ----
#pragma unroll
  for (int n = 0; n < 8; ++n)
#pragma unroll
    for (int e = 0; e < 4; ++e) {
      int iL = wi * 16 + hi * 4 + e;
      int j = (wj * 8 + n) * 16 + cg;
      unsigned short hv = f2bf_rne(p[n][e]);
      *(unsigned short*)(lds + PF_OFF + iL * PFP + j * 2) = hv;
      int us = iL + 255 - j;
      *(unsigned short*)(lds + MG_OFF + iL * MQP + us * 2) = hv;
    }
  {
    int cp = (t >> 2) & 63, half = t >> 8;
    int o = g * 128 + 64 + cp;
    float sc = qs[o], hh = qh[o];
    const float* src = qkv + ((size_t)b * OO + o) * NN;
#pragma unroll
    for (int r = 0; r < 8; ++r) {
      int ch = (t & 3) + half * 4 + 8 * r;
      float4 v = *(const float4*)(src + ch * 4);
      short4 s4 = make_short4(f2bf_rne(v.x * sc + hh), f2bf_rne(v.y * sc + hh),
                              f2bf_rne(v.z * sc + hh), f2bf_rne(v.w * sc + hh));
      *(short4*)(lds + VB_OFF + cp * PFP + ch * 8) = s4;
    }
    const float* srv = relp + (size_t)(64 + cp) * 512 + i0;
#pragma unroll
    for (int r = 0; r < 10; ++r) {
      int ch = (t & 3) + half * 4 + 8 * r;
      float4 v = *(const float4*)(srv + ch * 4);
      short4 s4 = make_short4(f2bf_rne(v.x), f2bf_rne(v.y), f2bf_rne(v.z), f2bf_rne(v.w));
      *(short4*)(lds + RV_OFF + cp * RVP + ch * 8) = s4;
    }
  }
  __syncthreads();

  // ---- sv = p.v^T, sve = Ps.Rv^T via MFMA (v-tiles split by wj) ----
  {
    int prow = wi * 16 + cg;
    bf16x8 af[8];
#pragma unroll
    for (int ks = 0; ks < 8; ++ks)
      af[ks] = *(const bf16x8*)(lds + PF_OFF + prow * PFP + ks * 64 + hi * 16);
#pragma unroll
    for (int n = 0; n < 2; ++n) {
      int ntv = wj * 2 + n;
      f32x4 acc = (f32x4){0.f, 0.f, 0.f, 0.f};
#pragma unroll
      for (int ks = 0; ks < 8; ++ks) {
        bf16x8 bfv = *(const bf16x8*)(lds + VB_OFF + (ntv * 16 + cg) * PFP + ks * 64 + hi * 16);
        acc = __builtin_amdgcn_mfma_f32_16x16x32_bf16(af[ks], bfv, acc, 0, 0, 0);
      }
      float* dst = svbuf + ((size_t)(b * 512 + g * 64 + ntv * 16 + cg)) * NN + i0 + wi * 16 + hi * 4;
      *(float4*)dst = make_float4(acc[0], acc[1], acc[2], acc[3]);
    }
    bf16x8 ae[10];
#pragma unroll
    for (int ks = 0; ks < 10; ++ks)
      ae[ks] = *(const bf16x8*)(lds + MG_OFF + prow * MQP + ks * 64 + hi * 16);
#pragma unroll
    for (int n = 0; n < 2; ++n) {
      int ntv = wj * 2 + n;
      f32x4 acc = (f32x4){0.f, 0.f, 0.f, 0.f};
#pragma unroll
      for (int ks = 0; ks < 10; ++ks) {
        bf16x8 bfr = *(const bf16x8*)(lds + RV_OFF + (ntv * 16 + cg) * RVP + ks * 64 + hi * 16);
        acc = __builtin_amdgcn_mfma_f32_16x16x32_bf16(ae[ks], bfr, acc, 0, 0, 0);
      }
      float* dst = svebuf + ((size_t)(b * 512 + g * 64 + ntv * 16 + cg)) * NN + i0 + wi * 16 + hi * 4;
      *(float4*)dst = make_float4(acc[0] * F_SVE, acc[1] * F_SVE, acc[2] * F_SVE, acc[3] * F_SVE);
    }
  }
}

// ---------------- K6: final BN stats over sv / sve ----------------
__global__ __launch_bounds__(256) void k_out_stats(const float* __restrict__ svbuf,
                                                   const float* __restrict__ svebuf,
                                                   const float* __restrict__ go,
                                                   const float* __restrict__ bo,
                                                   float* __restrict__ osc,
                                                   float* __restrict__ osh) {
  const int bid = blockIdx.x;
  const int arr = bid >> 9, pch = bid & 511;
  const float* buf = arr ? svebuf : svbuf;
  const int t = threadIdx.x;
  float s = 0.f, ss = 0.f;
  for (int b = 0; b < BB; ++b) {
    float v = buf[((size_t)b * 512 + pch) * NN + t];
    s += v; ss += v * v;
  }
#pragma unroll
  for (int m = 1; m < 64; m <<= 1) { s += __shfl_xor(s, m); ss += __shfl_xor(ss, m); }
  __shared__ float rs[4], rss[4];
  int wv = t >> 6;
  if ((t & 63) == 0) { rs[wv] = s; rss[wv] = ss; }
  __syncthreads();
  if (t == 0) {
    s = rs[0] + rs[1] + rs[2] + rs[3];
    ss = rss[0] + rss[1] + rss[2] + rss[3];
    const float inv = 1.f / 16384.f;
    float m = s * inv;
    float var = ss * inv - m * m;
    float r = rsqrtf(var + 1e-5f);
    int o = pch * 2 + arr;
    float sc = go[o] * r;
    osc[bid] = sc;
    osh[bid] = bo[o] - m * sc;
  }
}

// ---------------- K7: combine ----------------
__global__ __launch_bounds__(256) void k_final(const float* __restrict__ svbuf,
                                               const float* __restrict__ svebuf,
                                               const float* __restrict__ osc,
                                               const float* __restrict__ osh,
                                               float* __restrict__ out) {
  const size_t f = (size_t)blockIdx.x * 256 + threadIdx.x;
  const int pch = (int)((f >> 6) & 511);
  float4 a = ((const float4*)svbuf)[f];
  float4 e = ((const float4*)svebuf)[f];
  float s1 = osc[pch], h1 = osh[pch];
  float s2 = osc[512 + pch], h2 = osh[512 + pch];
  float hh = h1 + h2;
  float4 o;
  o.x = a.x * s1 + e.x * s2 + hh;
  o.y = a.y * s1 + e.y * s2 + hh;
  o.z = a.z * s1 + e.z * s2 + hh;
  o.w = a.w * s1 + e.w * s2 + hh;
  ((float4*)out)[f] = o;
}

extern "C" void kernel_launch(void* const* d_in, const int* in_sizes, int n_in,
                              void* d_out, int out_size, void* d_ws, size_t ws_size,
                              hipStream_t stream) {
  const float* x     = (const float*)d_in[0];
  const float* w     = (const float*)d_in[1];
  const float* rel   = (const float*)d_in[2];
  const float* g_qkv = (const float*)d_in[3];
  const float* b_qkv = (const float*)d_in[4];
  const float* g_sim = (const float*)d_in[5];
  const float* b_sim = (const float*)d_in[6];
  const float* g_out = (const float*)d_in[7];
  const float* b_out = (const float*)d_in[8];

  float* ws = (float*)d_ws;
  float* qkv      = ws;
  float* sv       = qkv + 16777216;
  float* sve      = sv + 8388608;
  float* qs       = sve + 8388608;
  float* qh       = qs + 1024;
  float* simacc   = qh + 1024;
  float* simscale = simacc + 48;
  float* simshift = simscale + 24;
  float* osc      = simshift + 8;
  float* osh      = osc + 1024;

  float* relp = (float*)d_out;

  float* Wbuf = sv;
  float* Rbuf = sv + 524288;

  hipFuncSetAttribute((const void*)k_pass2, hipFuncAttributeMaxDynamicSharedMemorySize, P2_LDS);

  hipMemsetAsync(simacc, 0, 48 * sizeof(float), stream);

  k_relpad<<<128, 256, 0, stream>>>(rel, relp);
  k_wprep<<<32, 256, 0, stream>>>(relp, Wbuf, Rbuf);
  k_qkv_gemm<<<dim3(2, 8, 64), 256, 0, stream>>>(x, w, qkv);
  k_qkv_stats<<<1024, 256, 0, stream>>>(qkv, g_qkv, b_qkv, qs, qh);
  k_simstats<<<512, 256, 0, stream>>>(qkv, Wbuf, Rbuf, qs, qh, simacc);
  k_sim_finalize<<<1, 32, 0, stream>>>(simacc, g_sim, b_sim, simscale, simshift);
  k_pass2<<<dim3(4, 512), 512, P2_LDS, stream>>>(qkv, relp, qs, qh, simscale, sv, sve);
  k_out_stats<<<1024, 256, 0, stream>>>(sv, sve, g_out, b_out, osc, osh);
  k_final<<<8192, 256, 0, stream>>>(sv, sve, osc, osh, (float*)d_out);
}